// Round 10
// baseline (364.322 us; speedup 1.0000x reference)
//
#include <hip/hip_runtime.h>
#include <hip/hip_bf16.h>
#include <hip/hip_cooperative_groups.h>
#include <math.h>

namespace cg = cooperative_groups;

#define D_  256
#define T_  2048
#define B_  4
#define M_  (B_*T_)
#define H_  4
#define HD_ 64

#define NC_ 64          // scan chunks
#define LCH (T_/NC_)    // 32 steps per chunk

enum { OP_NONE=0, OP_SIGMUL=1, OP_ADDAUX=2, OP_AXPBY=3, OP_GELU=4, OP_TANHHALF=5, OP_SCALE03=6 };

typedef unsigned short u16;
typedef short short8 __attribute__((ext_vector_type(8)));
typedef float f32x4  __attribute__((ext_vector_type(4)));

__device__ __forceinline__ float gelu_f(float x){ return 0.5f*x*(1.0f+erff(x*0.70710678118654752f)); }
__device__ __forceinline__ float sigmoid_f(float x){ return 1.0f/(1.0f+expf(-x)); }

__device__ __forceinline__ unsigned pk2(float a, float b){
    __hip_bfloat162 h = __float22bfloat162_rn(make_float2(a,b));
    union { __hip_bfloat162 h; unsigned u; } c; c.h = h; return c.u;
}
__device__ __forceinline__ float bfu(u16 u){ return __uint_as_float(((unsigned)u)<<16); }
__device__ __forceinline__ u16 bf1(float x){ return (u16)(pk2(x,x)&0xffffu); }

// weight-pack element offsets inside Wh (u16 elements)
#define OFF_QKV   0u        // fused qkv(768)+gkv(512) rows -> [1280,256]
#define OFF_MO    327680u
#define OFF_FG    393216u
#define OFF_GO    524288u
#define OFF_COMB  589824u
#define OFF_FFN1  786432u
#define OFF_FFN2  1048576u
#define OFF_TR1   1310720u
#define OFF_TR2   1572864u
#define OFF_P2S   1703936u  // stored TRANSPOSED: [k][n] = p2s_w[n][k]
#define OFF_S2P   1769472u  // stored TRANSPOSED
#define NWELEM    1835008u
#define NXELEM    2097152u

// ---------------------------------------------------------------------------
// One-shot fp32 -> bf16 conversion of all weights + X, qkv/gkv bias concat.
// p2s/s2p regions are written TRANSPOSED (for the weight-fusion precompute).
// ---------------------------------------------------------------------------
__global__ __launch_bounds__(256) void cvt_k(
    const float* __restrict__ qkv_w, const float* __restrict__ gkv_w,
    const float* __restrict__ qkv_b, const float* __restrict__ gkv_b,
    const float* __restrict__ mo_w,  const float* __restrict__ fg_w,
    const float* __restrict__ go_w,  const float* __restrict__ comb_w,
    const float* __restrict__ ffn1_w,const float* __restrict__ ffn2_w,
    const float* __restrict__ tr1_w, const float* __restrict__ tr2_w,
    const float* __restrict__ p2s_w, const float* __restrict__ s2p_w,
    const float* __restrict__ X,
    u16* __restrict__ Wh, u16* __restrict__ Xh, float* __restrict__ bq)
{
    size_t i = ((size_t)blockIdx.x*256 + threadIdx.x)*4;
    if (i < OFF_P2S){
        const float* s; size_t base;
        if      (i < OFF_MO)  { s=(i<196608)?qkv_w:gkv_w; base=(i<196608)?0:196608; }
        else if (i < OFF_FG)  { s=mo_w;   base=OFF_MO; }
        else if (i < OFF_GO)  { s=fg_w;   base=OFF_FG; }
        else if (i < OFF_COMB){ s=go_w;   base=OFF_GO; }
        else if (i < OFF_FFN1){ s=comb_w; base=OFF_COMB; }
        else if (i < OFF_FFN2){ s=ffn1_w; base=OFF_FFN1; }
        else if (i < OFF_TR1) { s=ffn2_w; base=OFF_FFN2; }
        else if (i < OFF_TR2) { s=tr1_w;  base=OFF_TR1; }
        else                  { s=tr2_w;  base=OFF_TR2; }
        float4 v = *(const float4*)(s + (i-base));
        *(uint2*)(Wh + i) = (uint2){ pk2(v.x,v.y), pk2(v.z,v.w) };
    } else if (i < NWELEM){
        const float* s = (i < OFF_S2P) ? p2s_w : s2p_w;
        const size_t base = (i < OFF_S2P) ? OFF_P2S : OFF_S2P;
        const size_t e = i - base;           // n*256 + k (k%4==0)
        const int n = (int)(e >> 8), k = (int)(e & 255);
        float4 v = *(const float4*)(s + e);
        u16* dst = Wh + base;
        dst[(size_t)(k+0)*256 + n] = bf1(v.x);
        dst[(size_t)(k+1)*256 + n] = bf1(v.y);
        dst[(size_t)(k+2)*256 + n] = bf1(v.z);
        dst[(size_t)(k+3)*256 + n] = bf1(v.w);
    } else if (i < NWELEM + NXELEM){
        size_t j = i - NWELEM;
        float4 v = *(const float4*)(X + j);
        *(uint2*)(Xh + j) = (uint2){ pk2(v.x,v.y), pk2(v.z,v.w) };
    } else if (i < NWELEM + NXELEM + 1280){
        size_t j = i - (NWELEM + NXELEM);
        #pragma unroll
        for (int k=0;k<4;++k){
            size_t e = j + k;
            bq[e] = (e < 768) ? qkv_b[e] : gkv_b[e-768];
        }
    }
}

// ---------------------------------------------------------------------------
// bf16 MFMA GEMM, register-staged pipeline, tile 128x64, BK=64,
// 512 threads = 8 waves (4M x 2N), mfma_f32_16x16x32_bf16, XCD swizzle.
// Explicit lda per operand (row stride); ldaux for the aux epilogue operand.
// ---------------------------------------------------------------------------
__global__ __launch_bounds__(512) void gemm_k(
    const u16* __restrict__ A0, int lda0, const u16* __restrict__ W0, int ldw0, int K0,
    const u16* __restrict__ A1, int lda1, const u16* __restrict__ W1, int ldw1, int K1,
    const u16* __restrict__ A2, int lda2, const u16* __restrict__ W2, int ldw2, int K2,
    const float* __restrict__ bias, const void* __restrict__ aux, int aux_bf16, int ldaux,
    void* __restrict__ C, int ldc, int c_bf16, int op, int ncol)
{
    __shared__ u16 As[128*64];
    __shared__ u16 Ws[64*64];

    const int q8   = gridDim.x >> 3;
    const int lid  = (blockIdx.x & 7)*q8 + (blockIdx.x >> 3);
    const int brow = lid / ncol;
    const int bcol = lid - brow*ncol;
    const int row0 = brow*128, col0 = bcol*64;

    const int tid  = threadIdx.x;
    const int lane = tid & 63, wid = tid >> 6;
    const int wm = (wid >> 1)*32, wn = (wid & 1)*32;
    const int l15 = lane & 15, l4 = lane >> 4;
    const int rowA = tid >> 2;            // 0..127
    const int scA  = (tid & 3) * 8;
    const int rowW = tid >> 3;            // 0..63
    const int scW  = (tid & 7) * 8;

    f32x4 acc[2][2];
    #pragma unroll
    for (int i=0;i<2;++i)
        #pragma unroll
        for (int j=0;j<2;++j) acc[i][j] = (f32x4){0.f,0.f,0.f,0.f};

    uint4 ra0, ra1, rw0;

    auto loadtile = [&](const u16* A, int lda, const u16* W, int ldw, int kb){
        const u16* ga = A + (size_t)(row0+rowA)*lda + kb + scA;
        ra0 = *(const uint4*)ga;
        ra1 = *(const uint4*)(ga + 32);
        rw0 = *(const uint4*)(W + (size_t)(col0+rowW)*ldw + kb + scW);
    };
    auto storetile = [&](){
        const int sw = (rowA&7)<<3;
        *(uint4*)&As[(rowA*64 + scA) ^ sw]      = ra0;
        *(uint4*)&As[(rowA*64 + scA + 32) ^ sw] = ra1;
        *(uint4*)&Ws[(rowW*64 + scW) ^ ((rowW&7)<<3)] = rw0;
    };
    auto mfma_tile = [&](){
        #pragma unroll
        for (int ks=0;ks<2;++ks){
            const int koff = ks*32 + l4*8;
            short8 af[2], bf[2];
            #pragma unroll
            for (int f=0;f<2;++f){
                const int ar = wm + f*16 + l15;
                af[f] = *(const short8*)&As[(ar*64 + koff) ^ ((ar&7)<<3)];
                const int brn = wn + f*16 + l15;
                bf[f] = *(const short8*)&Ws[(brn*64 + koff) ^ ((brn&7)<<3)];
            }
            #pragma unroll
            for (int fm=0;fm<2;++fm)
                #pragma unroll
                for (int fn=0;fn<2;++fn)
                    acc[fm][fn] = __builtin_amdgcn_mfma_f32_16x16x32_bf16(
                        af[fm], bf[fn], acc[fm][fn], 0, 0, 0);
        }
    };

    const u16* Ac = A0; const u16* Wc = W0; int ldac = lda0, ldwc = ldw0, Kc = K0, kb = 0;
    loadtile(Ac, ldac, Wc, ldwc, 0);
    while (true){
        __syncthreads();            // prev MFMA done; LDS free
        storetile();
        __syncthreads();            // staged tile visible
        int nkb = kb + 64;
        const u16* nA = Ac; const u16* nW = Wc; int nlda = ldac, nld = ldwc, nK = Kc;
        bool have_next = true;
        if (nkb >= Kc){
            if (Ac == A0 && A1){ nA = A1; nW = W1; nlda = lda1; nld = ldw1; nK = K1; nkb = 0; }
            else if (Ac == A1 && A2){ nA = A2; nW = W2; nlda = lda2; nld = ldw2; nK = K2; nkb = 0; }
            else have_next = false;
        }
        if (have_next) loadtile(nA, nlda, nW, nld, nkb);   // in flight across MFMA
        mfma_tile();
        if (!have_next) break;
        Ac = nA; Wc = nW; ldac = nlda; ldwc = nld; Kc = nK; kb = nkb;
    }

    #pragma unroll
    for (int fn=0;fn<2;++fn){
        const int n = col0 + wn + fn*16 + l15;
        const float bv = bias ? bias[n] : 0.f;
        #pragma unroll
        for (int fm=0;fm<2;++fm){
            #pragma unroll
            for (int j=0;j<4;++j){
                const int m = row0 + wm + fm*16 + l4*4 + j;
                float v = acc[fm][fn][j] + bv;
                if (op==OP_GELU)          v = gelu_f(v);
                else if (op==OP_TANHHALF) v = 0.5f*tanhf(v);
                else if (op==OP_SCALE03)  v = 0.3f*v;
                else if (op!=OP_NONE){
                    const size_t ai = (size_t)m*ldaux + n;
                    const float a = aux_bf16 ? bfu(((const u16*)aux)[ai])
                                             : ((const float*)aux)[ai];
                    if (op==OP_SIGMUL)      v = a*sigmoid_f(v);
                    else if (op==OP_ADDAUX) v = v + a;
                    else                    v = a + 0.3f*v;
                }
                if (c_bf16) ((u16*)C)[(size_t)m*ldc + n] = bf1(v);
                else        ((float*)C)[(size_t)m*ldc + n] = v;
            }
        }
    }
}

// ---------------------------------------------------------------------------
// Depthwise causal conv, K=8, pad left 7. bf16 in/out, 4 d's per thread.
// ---------------------------------------------------------------------------
__global__ __launch_bounds__(256) void conv_k(const u16* __restrict__ Xh,
    const float* __restrict__ w, const float* __restrict__ bias, u16* __restrict__ out)
{
    int idx = blockIdx.x*256 + threadIdx.x;       // over M*D/4
    int d4 = (idx & 63) * 4;
    int bt = idx >> 6;
    int t = bt & (T_-1);
    float a0 = bias[d4], a1 = bias[d4+1], a2 = bias[d4+2], a3 = bias[d4+3];
    const u16* xp = Xh + (size_t)bt*D_ + d4;
    #pragma unroll
    for (int j=0;j<8;++j){
        int tt = t - 7 + j;
        if (tt >= 0){
            uint2 v = *(const uint2*)(xp + (size_t)(j-7)*D_);
            a0 += bfu((u16)(v.x & 0xffff)) * w[(d4+0)*8 + j];
            a1 += bfu((u16)(v.x >> 16))    * w[(d4+1)*8 + j];
            a2 += bfu((u16)(v.y & 0xffff)) * w[(d4+2)*8 + j];
            a3 += bfu((u16)(v.y >> 16))    * w[(d4+3)*8 + j];
        }
    }
    *(uint2*)(out + (size_t)bt*D_ + d4) = (uint2){ pk2(a0,a1), pk2(a2,a3) };
}

// ---------------------------------------------------------------------------
// MFMA banded attention. Per block: (b, h, 64-query tile), 4 waves.
// ---------------------------------------------------------------------------
__global__ __launch_bounds__(256) void attn_k(const u16* __restrict__ QKVG,
    u16* __restrict__ MED)
{
    __shared__ u16 Kl[128*64];
    __shared__ u16 Ql[64*64];
    __shared__ u16 Vl[64*128];
    const int b = blockIdx.z, h = blockIdx.y;
    const int t0 = blockIdx.x * 64;
    const int kb0 = t0 - 64;
    const int tid = threadIdx.x;

    {
        const int r0 = tid >> 3, c8 = (tid & 7) * 8;
        #pragma unroll
        for (int rep=0;rep<4;++rep){
            const int r = r0 + rep*32;
            const int kg = kb0 + r;
            uint4 pk = {0,0,0,0}, pv = {0,0,0,0};
            if (kg >= 0){
                const u16* gp = QKVG + ((size_t)(b*T_ + kg))*1280 + h*HD_ + c8;
                pk = *(const uint4*)(gp + 256);
                pv = *(const uint4*)(gp + 512);
            }
            *(uint4*)&Kl[(r*64 + c8) ^ ((r&7)<<3)] = pk;
            const u16* pvu = (const u16*)&pv;
            #pragma unroll
            for (int j=0;j<8;++j){
                const int d = c8 + j;
                Vl[(d*128 + r) ^ ((d&15)<<3)] = pvu[j];
            }
        }
        #pragma unroll
        for (int rep=0;rep<2;++rep){
            const int r = r0 + rep*32;
            uint4 pq = *(const uint4*)(QKVG + ((size_t)(b*T_ + t0 + r))*1280 + h*HD_ + c8);
            *(uint4*)&Ql[(r*64 + c8) ^ ((r&7)<<3)] = pq;
        }
    }
    __syncthreads();

    const int lane = tid & 63, w = tid >> 6;
    const int l15 = lane & 15, l4 = lane >> 4;

    short8 bq[2];
    {
        const int qr = w*16 + l15;
        bq[0] = *(const short8*)&Ql[(qr*64 +      l4*8) ^ ((qr&7)<<3)];
        bq[1] = *(const short8*)&Ql[(qr*64 + 32 + l4*8) ^ ((qr&7)<<3)];
    }

    f32x4 s[8];
    #pragma unroll
    for (int kf=0;kf<8;++kf){
        const int kr = kf*16 + l15;
        short8 a0 = *(const short8*)&Kl[(kr*64 +      l4*8) ^ ((kr&7)<<3)];
        short8 a1 = *(const short8*)&Kl[(kr*64 + 32 + l4*8) ^ ((kr&7)<<3)];
        f32x4 acc = (f32x4){0.f,0.f,0.f,0.f};
        acc = __builtin_amdgcn_mfma_f32_16x16x32_bf16(a0, bq[0], acc, 0,0,0);
        acc = __builtin_amdgcn_mfma_f32_16x16x32_bf16(a1, bq[1], acc, 0,0,0);
        s[kf] = acc;
    }

    const int qg = t0 + w*16 + l15;
    float m = -1e30f;
    #pragma unroll
    for (int kf=0;kf<8;++kf){
        #pragma unroll
        for (int j=0;j<4;++j){
            const int kg = kb0 + kf*16 + l4*4 + j;
            const int diff = qg - kg;
            const float v = (kg >= 0 && diff >= 0 && diff < 64) ? s[kf][j]*0.125f : -1e30f;
            s[kf][j] = v;
            m = fmaxf(m, v);
        }
    }
    m = fmaxf(m, __shfl_xor(m,16));
    m = fmaxf(m, __shfl_xor(m,32));
    float lsum = 0.f;
    unsigned lo[8], hi[8];
    #pragma unroll
    for (int kf=0;kf<8;++kf){
        const float p0 = expf(s[kf][0]-m), p1 = expf(s[kf][1]-m);
        const float p2 = expf(s[kf][2]-m), p3 = expf(s[kf][3]-m);
        lsum += (p0+p1)+(p2+p3);
        lo[kf] = pk2(p0,p1);
        hi[kf] = pk2(p2,p3);
    }
    lsum += __shfl_xor(lsum,16);
    lsum += __shfl_xor(lsum,32);
    const float inv = 1.f/lsum;

    f32x4 o[4];
    #pragma unroll
    for (int df=0;df<4;++df) o[df] = (f32x4){0.f,0.f,0.f,0.f};
    const int baseLane = l15 + ((l4&1)<<5);
    const bool hiHalf = (l4>>1) != 0;
    #pragma unroll
    for (int kb=0;kb<4;++kb){
        const int x0 = __shfl((int)lo[2*kb],   baseLane);
        const int x1 = __shfl((int)hi[2*kb],   baseLane);
        const int x2 = __shfl((int)lo[2*kb],   baseLane+16);
        const int x3 = __shfl((int)hi[2*kb],   baseLane+16);
        const int y0 = __shfl((int)lo[2*kb+1], baseLane);
        const int y1 = __shfl((int)hi[2*kb+1], baseLane);
        const int y2 = __shfl((int)lo[2*kb+1], baseLane+16);
        const int y3 = __shfl((int)hi[2*kb+1], baseLane+16);
        int4 afi;
        afi.x = hiHalf ? y0 : x0;
        afi.y = hiHalf ? y1 : x1;
        afi.z = hiHalf ? y2 : x2;
        afi.w = hiHalf ? y3 : x3;
        union { int4 i; short8 s; } cv; cv.i = afi;
        #pragma unroll
        for (int df=0;df<4;++df){
            const int vr = df*16 + l15;
            short8 bv = *(const short8*)&Vl[(vr*128 + kb*32 + l4*8) ^ ((vr&15)<<3)];
            o[df] = __builtin_amdgcn_mfma_f32_16x16x32_bf16(cv.s, bv, o[df], 0,0,0);
        }
    }

    #pragma unroll
    for (int j=0;j<4;++j){
        const float invj = __shfl(inv, l4*4 + j);
        const int mrow = b*T_ + t0 + w*16 + l4*4 + j;
        u16* op = MED + (size_t)mrow*D_ + h*HD_ + l15;
        #pragma unroll
        for (int df=0;df<4;++df)
            op[df*16] = bf1(o[df][j] * invj);
    }
}

// ---------------------------------------------------------------------------
// Cooperative fused scans: phase1 per-chunk aggregate -> grid.sync ->
// phase2 own exclusive prefix + replay.  Grid (NC_, B_) x 256 threads.
// ---------------------------------------------------------------------------
__global__ __launch_bounds__(256) void scan1_coop(const u16* __restrict__ QKVG,
    float* __restrict__ CA, float* __restrict__ CC, u16* __restrict__ CONC)
{
    const int d = threadIdx.x, c = blockIdx.x, b = blockIdx.y;
    const u16* base = QKVG + ((size_t)(b*T_ + c*LCH))*1280;
    float sgk=0.f, sgkv=0.f;
    for (int t=0;t<LCH;++t){
        float gk = bfu(base[(size_t)t*1280 + 768 + d]);
        gk = gk > 0.f ? gk + 1.f : expf(gk);
        float gv = bfu(base[(size_t)t*1280 + 1024 + d]);
        sgk += gk; sgkv += gk*gv;
    }
    CA[((size_t)b*NC_ + c)*D_ + d] = sgk;
    CC[((size_t)b*NC_ + c)*D_ + d] = sgkv;
    cg::this_grid().sync();
    float pg = 0.f, pv = 0.f;
    for (int cc=0; cc<c; ++cc){
        pg += CA[((size_t)b*NC_ + cc)*D_ + d];
        pv += CC[((size_t)b*NC_ + cc)*D_ + d];
    }
    u16* out = CONC + ((size_t)(b*T_ + c*LCH))*D_ + d;
    for (int t=0;t<LCH;++t){
        float gk = bfu(base[(size_t)t*1280 + 768 + d]);
        gk = gk > 0.f ? gk + 1.f : expf(gk);
        float gv = bfu(base[(size_t)t*1280 + 1024 + d]);
        pg += gk; pv += gk*gv;
        out[(size_t)t*D_] = bf1(pv / (pg + 1e-5f));
    }
}

// EMA (bf16 in, bf16 out) fused; last chunk writes traj.
__global__ __launch_bounds__(256) void ema_coop(const u16* __restrict__ X,
    float* __restrict__ CARRY, u16* __restrict__ OUT, float alpha,
    float* __restrict__ traj)
{
    const int d = threadIdx.x, c = blockIdx.x, b = blockIdx.y;
    const u16* xp = X + ((size_t)(b*T_ + c*LCH))*D_ + d;
    float g = 0.f;
    for (int t=0;t<LCH;++t) g = 0.9f*g + alpha*bfu(xp[(size_t)t*D_]);
    CARRY[((size_t)b*NC_ + c)*D_ + d] = g;
    cg::this_grid().sync();
    const float dL = powf(0.9f, (float)LCH);
    g = 0.f;
    for (int cc=0; cc<c; ++cc) g = CARRY[((size_t)b*NC_ + cc)*D_ + d] + dL*g;
    u16* op = OUT + ((size_t)(b*T_ + c*LCH))*D_ + d;
    for (int t=0;t<LCH;++t){
        g = 0.9f*g + alpha*bfu(xp[(size_t)t*D_]);
        op[(size_t)t*D_] = bf1(g);
    }
    if (c == NC_-1) traj[b*D_ + d] = g;
}

// state EMA (bf16 in, fp32 out) fused, + analytic decayed initial state.
__global__ __launch_bounds__(256) void ema_state_coop(const u16* __restrict__ X,
    float* __restrict__ CARRY, const float* __restrict__ SEQ, float* __restrict__ OUT)
{
    const int d = threadIdx.x, c = blockIdx.x, b = blockIdx.y;
    const u16* xp = X + ((size_t)(b*T_ + c*LCH))*D_ + d;
    float a = 0.f;
    for (int t=0;t<LCH;++t) a = 0.9f*a + bfu(xp[(size_t)t*D_]);
    CARRY[((size_t)b*NC_ + c)*D_ + d] = a;
    cg::this_grid().sync();
    const float dL = powf(0.9f, (float)LCH);
    a = 0.f;
    for (int cc=0; cc<c; ++cc) a = CARRY[((size_t)b*NC_ + cc)*D_ + d] + dL*a;
    const float ss = SEQ[b*D_ + d];
    float dp = powf(0.9f, (float)(c*LCH + 1));
    float* op = OUT + ((size_t)(b*T_ + c*LCH))*D_ + d;
    for (int t=0;t<LCH;++t){
        a = 0.9f*a + bfu(xp[(size_t)t*D_]);
        op[(size_t)t*D_] = fmaf(ss, dp, a);
        dp *= 0.9f;
    }
}

// ---------------------------------------------------------------------------
// LayerNorms
// ---------------------------------------------------------------------------
__global__ __launch_bounds__(256) void ln_k(const float* __restrict__ in,
    const float* __restrict__ g, const float* __restrict__ b,
    float* __restrict__ out, u16* __restrict__ out2)
{
    int row  = blockIdx.x*4 + (threadIdx.x>>6);
    int lane = threadIdx.x & 63;
    const float* ip = in + (size_t)row*D_ + lane*4;
    float4 x = *(const float4*)ip;
    float s  = x.x+x.y+x.z+x.w;
    float s2 = x.x*x.x + x.y*x.y + x.z*x.z + x.w*x.w;
    #pragma unroll
    for (int o=1;o<64;o<<=1){ s += __shfl_xor(s,o); s2 += __shfl_xor(s2,o); }
    float mean = s * (1.f/256.f);
    float var  = s2 * (1.f/256.f) - mean*mean;
    float rs = rsqrtf(var + 1e-5f);
    int db = lane*4;
    float4 r;
    r.x=(x.x-mean)*rs*g[db+0]+b[db+0];
    r.y=(x.y-mean)*rs*g[db+1]+b[db+1];
    r.z=(x.z-mean)*rs*g[db+2]+b[db+2];
    r.w=(x.w-mean)*rs*g[db+3]+b[db+3];
    if (out)
        *(float4*)(out + (size_t)row*D_ + db) = r;
    if (out2)
        *(uint2*)(out2 + (size_t)row*D_ + db) = (uint2){ pk2(r.x,r.y), pk2(r.z,r.w) };
}

__global__ __launch_bounds__(256) void ln3_k(const float* __restrict__ in,
    const float* __restrict__ g3, const float* __restrict__ b3, u16* __restrict__ states,
    const float* __restrict__ g4, const float* __restrict__ b4, float* __restrict__ fsout)
{
    int row  = blockIdx.x*4 + (threadIdx.x>>6);
    int lane = threadIdx.x & 63;
    const float* ip = in + (size_t)row*D_ + lane*4;
    float4 x = *(const float4*)ip;
    float s  = x.x+x.y+x.z+x.w;
    float s2 = x.x*x.x + x.y*x.y + x.z*x.z + x.w*x.w;
    #pragma unroll
    for (int o=1;o<64;o<<=1){ s += __shfl_xor(s,o); s2 += __shfl_xor(s2,o); }
    float mean = s * (1.f/256.f);
    float var  = s2 * (1.f/256.f) - mean*mean;
    float rs = rsqrtf(var + 1e-5f);
    int db = lane*4;
    float4 st;
    st.x=(x.x-mean)*rs*g3[db+0]+b3[db+0];
    st.y=(x.y-mean)*rs*g3[db+1]+b3[db+1];
    st.z=(x.z-mean)*rs*g3[db+2]+b3[db+2];
    st.w=(x.w-mean)*rs*g3[db+3]+b3[db+3];
    *(uint2*)(states + (size_t)row*D_ + db) = (uint2){ pk2(st.x,st.y), pk2(st.z,st.w) };

    if ((row & (T_-1)) == T_-1){
        float u  = st.x+st.y+st.z+st.w;
        float u2 = st.x*st.x + st.y*st.y + st.z*st.z + st.w*st.w;
        #pragma unroll
        for (int o=1;o<64;o<<=1){ u += __shfl_xor(u,o); u2 += __shfl_xor(u2,o); }
        float m2 = u * (1.f/256.f);
        float v2 = u2 * (1.f/256.f) - m2*m2;
        float r2 = rsqrtf(v2 + 1e-5f);
        float4 fs;
        fs.x=(st.x-m2)*r2*g4[db+0]+b4[db+0];
        fs.y=(st.y-m2)*r2*g4[db+1]+b4[db+1];
        fs.z=(st.z-m2)*r2*g4[db+2]+b4[db+2];
        fs.w=(st.w-m2)*r2*g4[db+3]+b4[db+3];
        *(float4*)(fsout + (size_t)(row>>11)*D_ + db) = fs;
    }
}

// ---------------------------------------------------------------------------
extern "C" void kernel_launch(void* const* d_in, const int* in_sizes, int n_in,
                              void* d_out, int out_size, void* d_ws, size_t ws_size,
                              hipStream_t stream)
{
    const float* X     = (const float*)d_in[0];
    const float* SEQ   = (const float*)d_in[1];
    const float* conv_w= (const float*)d_in[3];
    const float* conv_b= (const float*)d_in[4];
    const float* qkv_w = (const float*)d_in[5];
    const float* qkv_b = (const float*)d_in[6];
    const float* mo_w  = (const float*)d_in[7];
    const float* mo_b  = (const float*)d_in[8];
    const float* fg_w  = (const float*)d_in[9];
    const float* fg_b  = (const float*)d_in[10];
    const float* gkv_w = (const float*)d_in[11];
    const float* gkv_b = (const float*)d_in[12];
    const float* go_w  = (const float*)d_in[13];
    const float* go_b  = (const float*)d_in[14];
    const float* comb_w= (const float*)d_in[15];
    const float* comb_b= (const float*)d_in[16];
    const float* ffn1_w= (const float*)d_in[17];
    const float* ffn1_b= (const float*)d_in[18];
    const float* ffn2_w= (const float*)d_in[19];
    const float* ffn2_b= (const float*)d_in[20];
    const float* tr1_w = (const float*)d_in[21];
    const float* tr1_b = (const float*)d_in[22];
    const float* tr2_w = (const float*)d_in[23];
    const float* tr2_b = (const float*)d_in[24];
    const float* p2s_w = (const float*)d_in[25];
    const float* p2s_b = (const float*)d_in[26];
    const float* s2p_w = (const float*)d_in[27];
    const float* s2p_b = (const float*)d_in[28];
    const float* ln1_g = (const float*)d_in[29];
    const float* ln1_b = (const float*)d_in[30];
    const float* ln2_g = (const float*)d_in[31];
    const float* ln2_b = (const float*)d_in[32];
    const float* ln3_g = (const float*)d_in[33];
    const float* ln3_b = (const float*)d_in[34];
    const float* ln4_g = (const float*)d_in[35];
    const float* ln4_b = (const float*)d_in[36];

    // -------- workspace carve (256-byte aligned chunks) --------
    char* p = (char*)d_ws;
    auto alloc = [&](size_t bytes)->char*{ char* r = p; p += (bytes + 255) & ~(size_t)255; return r; };

    u16*   QKVG = (u16*)  alloc((size_t)M_*1280*2);
    u16*   Wh   = (u16*)  alloc((size_t)NWELEM*2);
    float* bq   = (float*)alloc(1280*4);
    u16*   WA   = (u16*)  alloc((size_t)512*256*2);   // tr1a + 0.3*tr1a@p2s
    u16*   WF   = (u16*)  alloc((size_t)1024*256*2);  // 0.3*ffn1@s2p
    u16*   Xh   = (u16*)  alloc((size_t)M_*256*2);
    u16*   MED  = (u16*)  alloc((size_t)M_*256*2);
    u16*   MED2 = (u16*)  alloc((size_t)M_*256*2);
    u16*   LH   = (u16*)  alloc((size_t)M_*256*2);
    u16*   CONC = (u16*)  alloc((size_t)M_*256*2);
    u16*   GOUT = (u16*)  alloc((size_t)M_*256*2);
    u16*   MOUT = (u16*)  alloc((size_t)M_*256*2);
    float* PRE1 = (float*)alloc((size_t)M_*256*4);
    u16*   PRh  = (u16*)  alloc((size_t)M_*256*2);
    u16*   GSUM = (u16*)  alloc((size_t)M_*256*2);
    u16*   H1   = (u16*)  alloc((size_t)M_*512*2);
    u16*   SCALEDh=(u16*) alloc((size_t)M_*256*2);
    float* PRE3 = (float*)alloc((size_t)M_*256*4);
    u16*   STATESh=(u16*) alloc((size_t)M_*256*2);
    u16*   H2   = (u16*)  alloc((size_t)M_*1024*2);
    float* PRE2 = (float*)alloc((size_t)M_*256*4);
    float* CAR0 = (float*)alloc((size_t)B_*NC_*D_*4);
    float* CAR1 = (float*)alloc((size_t)B_*NC_*D_*4);

    float* out_pr = (float*)d_out;
    float* out_fs = out_pr + (size_t)M_*256;
    float* out_tj = out_fs + B_*256;

    const dim3 blk256(256), blk512(512);
    const dim3 scan_grid(NC_, B_);
    const int NRg = M_/128;   // 64 row tiles

    // 0. convert weights + X to bf16 (p2s/s2p transposed), bias concat
    cvt_k<<<dim3(3842), blk256, 0, stream>>>(
        qkv_w, gkv_w, qkv_b, gkv_b, mo_w, fg_w, go_w, comb_w,
        ffn1_w, ffn2_w, tr1_w, tr2_w, p2s_w, s2p_w, X, Wh, Xh, bq);
    // 0a. WA = tr1a + 0.3*tr1a@p2s   (M=512, N=256, K=256)
    gemm_k<<<dim3(16), blk512, 0, stream>>>(
        Wh+OFF_TR1, 512, Wh+OFF_P2S, 256, 256,
        nullptr,0,nullptr,0,0,  nullptr,0,nullptr,0,0,
        nullptr, Wh+OFF_TR1, 1, 512, WA, 256, 1, OP_AXPBY, 4);
    // 0b. WF = 0.3*ffn1@s2p          (M=1024, N=256, K=256)
    gemm_k<<<dim3(32), blk512, 0, stream>>>(
        Wh+OFF_FFN1, 256, Wh+OFF_S2P, 256, 256,
        nullptr,0,nullptr,0,0,  nullptr,0,nullptr,0,0,
        nullptr, nullptr, 0, 256, WF, 256, 1, OP_SCALE03, 4);
    // 1. fused qkv+gkv projection -> QKVG (bf16)
    gemm_k<<<dim3(NRg*20), blk512, 0, stream>>>(
        Xh, 256, Wh+OFF_QKV, 256, 256,
        nullptr,0,nullptr,0,0,  nullptr,0,nullptr,0,0,
        bq, nullptr, 0, 256, QKVG, 1280, 1, OP_NONE, 20);
    // 2. local_history (depthwise conv) -> LH bf16
    conv_k<<<dim3(M_*D_/1024), blk256, 0, stream>>>(Xh, conv_w, conv_b, LH);
    // 3. banded attention -> MED bf16
    attn_k<<<dim3(T_/64, H_, B_), blk256, 0, stream>>>(QKVG, MED);
    // 4. mo projection -> MED2 bf16
    gemm_k<<<dim3(NRg*4), blk512, 0, stream>>>(
        MED, 256, Wh+OFF_MO, 256, 256,
        nullptr,0,nullptr,0,0,  nullptr,0,nullptr,0,0,
        mo_b, nullptr, 0, 256, MED2, 256, 1, OP_NONE, 4);
    // 5. concepts scan (cooperative fused) -> CONC bf16
    {
        void* args[] = {(void*)&QKVG, (void*)&CAR0, (void*)&CAR1, (void*)&CONC};
        hipLaunchCooperativeKernel(reinterpret_cast<void*>(scan1_coop),
                                   scan_grid, blk256, args, 0, stream);
    }
    // 6. global_out -> GOUT bf16
    gemm_k<<<dim3(NRg*4), blk512, 0, stream>>>(
        CONC, 256, Wh+OFF_GO, 256, 256,
        nullptr,0,nullptr,0,0,  nullptr,0,nullptr,0,0,
        go_b, nullptr, 0, 256, GOUT, 256, 1, OP_NONE, 4);
    // 7. medium_out = MED2 * sigmoid([X,MED2]@fg^T + b) -> MOUT bf16
    gemm_k<<<dim3(NRg*4), blk512, 0, stream>>>(
        Xh, 256, Wh+OFF_FG, 512, 256,
        MED2, 256, Wh+OFF_FG+256, 512, 256,  nullptr,0,nullptr,0,0,
        fg_b, MED2, 1, 256, MOUT, 256, 1, OP_SIGMUL, 4);
    // 8. pre_ln1 = X + [LH,MOUT,GOUT]@comb^T + b -> PRE1 fp32
    gemm_k<<<dim3(NRg*4), blk512, 0, stream>>>(
        LH, 256, Wh+OFF_COMB, 768, 256,
        MOUT, 256, Wh+OFF_COMB+256, 768, 256,
        GOUT, 256, Wh+OFF_COMB+512, 768, 256,
        comb_b, X, 0, 256, PRE1, 256, 0, OP_ADDAUX, 4);
    // 9. pr = LN1 -> PRh bf16
    ln_k<<<dim3(M_/4), blk256, 0, stream>>>(PRE1, ln1_g, ln1_b, nullptr, PRh);
    // 10. global_summary EMA (cooperative fused) -> GSUM bf16 + traj
    {
        float alpha = 0.1f;
        void* args[] = {(void*)&PRh, (void*)&CAR0, (void*)&GSUM, (void*)&alpha, (void*)&out_tj};
        hipLaunchCooperativeKernel(reinterpret_cast<void*>(ema_coop),
                                   scan_grid, blk256, args, 0, stream);
    }
    // 11. H1 = gelu(pr@WA^T + gsum@tr1b^T + b)   (p2s folded into WA)
    gemm_k<<<dim3(NRg*8), blk512, 0, stream>>>(
        PRh, 256, WA, 256, 256,
        GSUM, 256, Wh+OFF_TR1+256, 512, 256,  nullptr,0,nullptr,0,0,
        tr1_b, nullptr, 0, 256, H1, 512, 1, OP_GELU, 8);
    // 12. scaled = 0.5*tanh(H1@tr2^T + b) -> SCALEDh bf16
    gemm_k<<<dim3(NRg*4), blk512, 0, stream>>>(
        H1, 512, Wh+OFF_TR2, 512, 512,
        nullptr,0,nullptr,0,0,  nullptr,0,nullptr,0,0,
        tr2_b, nullptr, 0, 256, SCALEDh, 256, 1, OP_TANHHALF, 4);
    // 13. state EMA + decayed initial (cooperative fused) -> PRE3 fp32
    {
        void* args[] = {(void*)&SCALEDh, (void*)&CAR0, (void*)&SEQ, (void*)&PRE3};
        hipLaunchCooperativeKernel(reinterpret_cast<void*>(ema_state_coop),
                                   scan_grid, blk256, args, 0, stream);
    }
    // 14. states = LN3 -> STATESh bf16; final_state = LN4(states[-1]) -> out
    ln3_k<<<dim3(M_/4), blk256, 0, stream>>>(PRE3, ln3_g, ln3_b, STATESh, ln4_g, ln4_b, out_fs);
    // 15. H2 = gelu(pr@ffn1^T + states@WF^T + b)  (s2p folded into WF)
    gemm_k<<<dim3(NRg*16), blk512, 0, stream>>>(
        PRh, 256, Wh+OFF_FFN1, 256, 256,
        STATESh, 256, WF, 256, 256,  nullptr,0,nullptr,0,0,
        ffn1_b, nullptr, 0, 256, H2, 1024, 1, OP_GELU, 16);
    // 16. pre_ln2 = pr + H2@ffn2^T + b -> PRE2 fp32
    gemm_k<<<dim3(NRg*4), blk512, 0, stream>>>(
        H2, 1024, Wh+OFF_FFN2, 1024, 1024,
        nullptr,0,nullptr,0,0,  nullptr,0,nullptr,0,0,
        ffn2_b, PRh, 1, 256, PRE2, 256, 0, OP_ADDAUX, 4);
    // 17. pr_out = LN2 -> d_out
    ln_k<<<dim3(M_/4), blk256, 0, stream>>>(PRE2, ln2_g, ln2_b, out_pr, nullptr);
}

// Round 11
// 275.921 us; speedup vs baseline: 1.3204x; 1.3204x over previous
//
#include <hip/hip_runtime.h>
#include <hip/hip_bf16.h>
#include <math.h>

#define D_  256
#define T_  2048
#define B_  4
#define M_  (B_*T_)
#define H_  4
#define HD_ 64

#define NC_ 64          // scan chunks
#define LCH (T_/NC_)    // 32 steps per chunk

enum { OP_NONE=0, OP_SIGMUL=1, OP_ADDAUX=2, OP_AXPBY=3, OP_GELU=4, OP_TANHHALF=5, OP_SCALE03=6 };

typedef unsigned short u16;
typedef short short8 __attribute__((ext_vector_type(8)));
typedef float f32x4  __attribute__((ext_vector_type(4)));

__device__ __forceinline__ float gelu_f(float x){ return 0.5f*x*(1.0f+erff(x*0.70710678118654752f)); }
__device__ __forceinline__ float sigmoid_f(float x){ return 1.0f/(1.0f+expf(-x)); }

__device__ __forceinline__ unsigned pk2(float a, float b){
    __hip_bfloat162 h = __float22bfloat162_rn(make_float2(a,b));
    union { __hip_bfloat162 h; unsigned u; } c; c.h = h; return c.u;
}
__device__ __forceinline__ float bfu(u16 u){ return __uint_as_float(((unsigned)u)<<16); }
__device__ __forceinline__ u16 bf1(float x){ return (u16)(pk2(x,x)&0xffffu); }

// weight-pack element offsets inside Wh (u16 elements)
#define OFF_QKV   0u        // fused qkv(768)+gkv(512) rows -> [1280,256]
#define OFF_MO    327680u
#define OFF_FG    393216u
#define OFF_GO    524288u   // stored TRANSPOSED: [k][n] = go_w[n][k]
#define OFF_COMB  589824u
#define OFF_FFN1  786432u
#define OFF_FFN2  1048576u
#define OFF_TR1   1310720u
#define OFF_TR2   1572864u
#define OFF_P2S   1703936u  // stored TRANSPOSED
#define OFF_S2P   1769472u  // stored TRANSPOSED
#define NWELEM    1835008u
#define NXELEM    2097152u

// ---------------------------------------------------------------------------
// One-shot fp32 -> bf16 conversion of weights + X; go/p2s/s2p transposed;
// qkv/gkv bias concat; comb bias folded with combC@go_b.
// ---------------------------------------------------------------------------
__global__ __launch_bounds__(256) void cvt_k(
    const float* __restrict__ qkv_w, const float* __restrict__ gkv_w,
    const float* __restrict__ qkv_b, const float* __restrict__ gkv_b,
    const float* __restrict__ mo_w,  const float* __restrict__ fg_w,
    const float* __restrict__ go_w,  const float* __restrict__ go_b,
    const float* __restrict__ comb_w, const float* __restrict__ comb_b,
    const float* __restrict__ ffn1_w,const float* __restrict__ ffn2_w,
    const float* __restrict__ tr1_w, const float* __restrict__ tr2_w,
    const float* __restrict__ p2s_w, const float* __restrict__ s2p_w,
    const float* __restrict__ X,
    u16* __restrict__ Wh, u16* __restrict__ Xh, float* __restrict__ bq,
    float* __restrict__ bcomb)
{
    size_t i = ((size_t)blockIdx.x*256 + threadIdx.x)*4;
    if (i < OFF_GO){
        const float* s; size_t base;
        if      (i < OFF_MO)  { s=(i<196608)?qkv_w:gkv_w; base=(i<196608)?0:196608; }
        else if (i < OFF_FG)  { s=mo_w;   base=OFF_MO; }
        else                  { s=fg_w;   base=OFF_FG; }
        float4 v = *(const float4*)(s + (i-base));
        *(uint2*)(Wh + i) = (uint2){ pk2(v.x,v.y), pk2(v.z,v.w) };
    } else if (i < OFF_COMB){
        // go transposed
        const size_t e = i - OFF_GO;          // n*256 + k
        const int n = (int)(e >> 8), k = (int)(e & 255);
        float4 v = *(const float4*)(go_w + e);
        u16* dst = Wh + OFF_GO;
        dst[(size_t)(k+0)*256 + n] = bf1(v.x);
        dst[(size_t)(k+1)*256 + n] = bf1(v.y);
        dst[(size_t)(k+2)*256 + n] = bf1(v.z);
        dst[(size_t)(k+3)*256 + n] = bf1(v.w);
    } else if (i < OFF_P2S){
        const float* s; size_t base;
        if      (i < OFF_FFN1){ s=comb_w; base=OFF_COMB; }
        else if (i < OFF_FFN2){ s=ffn1_w; base=OFF_FFN1; }
        else if (i < OFF_TR1) { s=ffn2_w; base=OFF_FFN2; }
        else if (i < OFF_TR2) { s=tr1_w;  base=OFF_TR1; }
        else                  { s=tr2_w;  base=OFF_TR2; }
        float4 v = *(const float4*)(s + (i-base));
        *(uint2*)(Wh + i) = (uint2){ pk2(v.x,v.y), pk2(v.z,v.w) };
    } else if (i < NWELEM){
        const float* s = (i < OFF_S2P) ? p2s_w : s2p_w;
        const size_t base = (i < OFF_S2P) ? OFF_P2S : OFF_S2P;
        const size_t e = i - base;            // n*256 + k
        const int n = (int)(e >> 8), k = (int)(e & 255);
        float4 v = *(const float4*)(s + e);
        u16* dst = Wh + base;
        dst[(size_t)(k+0)*256 + n] = bf1(v.x);
        dst[(size_t)(k+1)*256 + n] = bf1(v.y);
        dst[(size_t)(k+2)*256 + n] = bf1(v.z);
        dst[(size_t)(k+3)*256 + n] = bf1(v.w);
    } else if (i < NWELEM + NXELEM){
        size_t j = i - NWELEM;
        float4 v = *(const float4*)(X + j);
        *(uint2*)(Xh + j) = (uint2){ pk2(v.x,v.y), pk2(v.z,v.w) };
    } else if (i < NWELEM + NXELEM + 1280){
        size_t j = i - (NWELEM + NXELEM);
        #pragma unroll
        for (int k=0;k<4;++k){
            size_t e = j + k;
            bq[e] = (e < 768) ? qkv_b[e] : gkv_b[e-768];
        }
    } else if (i < NWELEM + NXELEM + 1280 + 256){
        size_t j = i - (NWELEM + NXELEM + 1280);
        #pragma unroll
        for (int k=0;k<4;++k){
            const int c = (int)j + k;
            float acc = comb_b[c];
            const float* cw = comb_w + (size_t)c*768 + 512;
            for (int n=0;n<256;++n) acc += cw[n]*go_b[n];
            bcomb[c] = acc;
        }
    }
}

// ---------------------------------------------------------------------------
// bf16 MFMA GEMM, register-staged pipeline, tile 128x64, BK=64,
// 512 threads = 8 waves (4M x 2N), mfma_f32_16x16x32_bf16, XCD swizzle.
// ---------------------------------------------------------------------------
__global__ __launch_bounds__(512) void gemm_k(
    const u16* __restrict__ A0, int lda0, const u16* __restrict__ W0, int ldw0, int K0,
    const u16* __restrict__ A1, int lda1, const u16* __restrict__ W1, int ldw1, int K1,
    const u16* __restrict__ A2, int lda2, const u16* __restrict__ W2, int ldw2, int K2,
    const float* __restrict__ bias, const void* __restrict__ aux, int aux_bf16, int ldaux,
    void* __restrict__ C, int ldc, int c_bf16, int op, int ncol)
{
    __shared__ u16 As[128*64];
    __shared__ u16 Ws[64*64];

    const int q8   = gridDim.x >> 3;
    const int lid  = (blockIdx.x & 7)*q8 + (blockIdx.x >> 3);
    const int brow = lid / ncol;
    const int bcol = lid - brow*ncol;
    const int row0 = brow*128, col0 = bcol*64;

    const int tid  = threadIdx.x;
    const int lane = tid & 63, wid = tid >> 6;
    const int wm = (wid >> 1)*32, wn = (wid & 1)*32;
    const int l15 = lane & 15, l4 = lane >> 4;
    const int rowA = tid >> 2;            // 0..127
    const int scA  = (tid & 3) * 8;
    const int rowW = tid >> 3;            // 0..63
    const int scW  = (tid & 7) * 8;

    f32x4 acc[2][2];
    #pragma unroll
    for (int i=0;i<2;++i)
        #pragma unroll
        for (int j=0;j<2;++j) acc[i][j] = (f32x4){0.f,0.f,0.f,0.f};

    uint4 ra0, ra1, rw0;

    auto loadtile = [&](const u16* A, int lda, const u16* W, int ldw, int kb){
        const u16* ga = A + (size_t)(row0+rowA)*lda + kb + scA;
        ra0 = *(const uint4*)ga;
        ra1 = *(const uint4*)(ga + 32);
        rw0 = *(const uint4*)(W + (size_t)(col0+rowW)*ldw + kb + scW);
    };
    auto storetile = [&](){
        const int sw = (rowA&7)<<3;
        *(uint4*)&As[(rowA*64 + scA) ^ sw]      = ra0;
        *(uint4*)&As[(rowA*64 + scA + 32) ^ sw] = ra1;
        *(uint4*)&Ws[(rowW*64 + scW) ^ ((rowW&7)<<3)] = rw0;
    };
    auto mfma_tile = [&](){
        #pragma unroll
        for (int ks=0;ks<2;++ks){
            const int koff = ks*32 + l4*8;
            short8 af[2], bf[2];
            #pragma unroll
            for (int f=0;f<2;++f){
                const int ar = wm + f*16 + l15;
                af[f] = *(const short8*)&As[(ar*64 + koff) ^ ((ar&7)<<3)];
                const int brn = wn + f*16 + l15;
                bf[f] = *(const short8*)&Ws[(brn*64 + koff) ^ ((brn&7)<<3)];
            }
            #pragma unroll
            for (int fm=0;fm<2;++fm)
                #pragma unroll
                for (int fn=0;fn<2;++fn)
                    acc[fm][fn] = __builtin_amdgcn_mfma_f32_16x16x32_bf16(
                        af[fm], bf[fn], acc[fm][fn], 0, 0, 0);
        }
    };

    const u16* Ac = A0; const u16* Wc = W0; int ldac = lda0, ldwc = ldw0, Kc = K0, kb = 0;
    loadtile(Ac, ldac, Wc, ldwc, 0);
    while (true){
        __syncthreads();            // prev MFMA done; LDS free
        storetile();
        __syncthreads();            // staged tile visible
        int nkb = kb + 64;
        const u16* nA = Ac; const u16* nW = Wc; int nlda = ldac, nld = ldwc, nK = Kc;
        bool have_next = true;
        if (nkb >= Kc){
            if (Ac == A0 && A1){ nA = A1; nW = W1; nlda = lda1; nld = ldw1; nK = K1; nkb = 0; }
            else if (Ac == A1 && A2){ nA = A2; nW = W2; nlda = lda2; nld = ldw2; nK = K2; nkb = 0; }
            else have_next = false;
        }
        if (have_next) loadtile(nA, nlda, nW, nld, nkb);   // in flight across MFMA
        mfma_tile();
        if (!have_next) break;
        Ac = nA; Wc = nW; ldac = nlda; ldwc = nld; Kc = nK; kb = nkb;
    }

    #pragma unroll
    for (int fn=0;fn<2;++fn){
        const int n = col0 + wn + fn*16 + l15;
        const float bv = bias ? bias[n] : 0.f;
        #pragma unroll
        for (int fm=0;fm<2;++fm){
            #pragma unroll
            for (int j=0;j<4;++j){
                const int m = row0 + wm + fm*16 + l4*4 + j;
                float v = acc[fm][fn][j] + bv;
                if (op==OP_GELU)          v = gelu_f(v);
                else if (op==OP_TANHHALF) v = 0.5f*tanhf(v);
                else if (op==OP_SCALE03)  v = 0.3f*v;
                else if (op!=OP_NONE){
                    const size_t ai = (size_t)m*ldaux + n;
                    const float a = aux_bf16 ? bfu(((const u16*)aux)[ai])
                                             : ((const float*)aux)[ai];
                    if (op==OP_SIGMUL)      v = a*sigmoid_f(v);
                    else if (op==OP_ADDAUX) v = v + a;
                    else                    v = a + 0.3f*v;
                }
                if (c_bf16) ((u16*)C)[(size_t)m*ldc + n] = bf1(v);
                else        ((float*)C)[(size_t)m*ldc + n] = v;
            }
        }
    }
}

// ---------------------------------------------------------------------------
// Depthwise causal conv, K=8, pad left 7. bf16 in/out, 4 d's per thread.
// ---------------------------------------------------------------------------
__global__ __launch_bounds__(256) void conv_k(const u16* __restrict__ Xh,
    const float* __restrict__ w, const float* __restrict__ bias, u16* __restrict__ out)
{
    int idx = blockIdx.x*256 + threadIdx.x;       // over M*D/4
    int d4 = (idx & 63) * 4;
    int bt = idx >> 6;
    int t = bt & (T_-1);
    float a0 = bias[d4], a1 = bias[d4+1], a2 = bias[d4+2], a3 = bias[d4+3];
    const u16* xp = Xh + (size_t)bt*D_ + d4;
    #pragma unroll
    for (int j=0;j<8;++j){
        int tt = t - 7 + j;
        if (tt >= 0){
            uint2 v = *(const uint2*)(xp + (size_t)(j-7)*D_);
            a0 += bfu((u16)(v.x & 0xffff)) * w[(d4+0)*8 + j];
            a1 += bfu((u16)(v.x >> 16))    * w[(d4+1)*8 + j];
            a2 += bfu((u16)(v.y & 0xffff)) * w[(d4+2)*8 + j];
            a3 += bfu((u16)(v.y >> 16))    * w[(d4+3)*8 + j];
        }
    }
    *(uint2*)(out + (size_t)bt*D_ + d4) = (uint2){ pk2(a0,a1), pk2(a2,a3) };
}

// ---------------------------------------------------------------------------
// MFMA banded attention. Per block: (b, h, 64-query tile), 4 waves.
// ---------------------------------------------------------------------------
__global__ __launch_bounds__(256) void attn_k(const u16* __restrict__ QKVG,
    u16* __restrict__ MED)
{
    __shared__ u16 Kl[128*64];
    __shared__ u16 Ql[64*64];
    __shared__ u16 Vl[64*128];
    const int b = blockIdx.z, h = blockIdx.y;
    const int t0 = blockIdx.x * 64;
    const int kb0 = t0 - 64;
    const int tid = threadIdx.x;

    {
        const int r0 = tid >> 3, c8 = (tid & 7) * 8;
        #pragma unroll
        for (int rep=0;rep<4;++rep){
            const int r = r0 + rep*32;
            const int kg = kb0 + r;
            uint4 pk = {0,0,0,0}, pv = {0,0,0,0};
            if (kg >= 0){
                const u16* gp = QKVG + ((size_t)(b*T_ + kg))*1280 + h*HD_ + c8;
                pk = *(const uint4*)(gp + 256);
                pv = *(const uint4*)(gp + 512);
            }
            *(uint4*)&Kl[(r*64 + c8) ^ ((r&7)<<3)] = pk;
            const u16* pvu = (const u16*)&pv;
            #pragma unroll
            for (int j=0;j<8;++j){
                const int d = c8 + j;
                Vl[(d*128 + r) ^ ((d&15)<<3)] = pvu[j];
            }
        }
        #pragma unroll
        for (int rep=0;rep<2;++rep){
            const int r = r0 + rep*32;
            uint4 pq = *(const uint4*)(QKVG + ((size_t)(b*T_ + t0 + r))*1280 + h*HD_ + c8);
            *(uint4*)&Ql[(r*64 + c8) ^ ((r&7)<<3)] = pq;
        }
    }
    __syncthreads();

    const int lane = tid & 63, w = tid >> 6;
    const int l15 = lane & 15, l4 = lane >> 4;

    short8 bq[2];
    {
        const int qr = w*16 + l15;
        bq[0] = *(const short8*)&Ql[(qr*64 +      l4*8) ^ ((qr&7)<<3)];
        bq[1] = *(const short8*)&Ql[(qr*64 + 32 + l4*8) ^ ((qr&7)<<3)];
    }

    f32x4 s[8];
    #pragma unroll
    for (int kf=0;kf<8;++kf){
        const int kr = kf*16 + l15;
        short8 a0 = *(const short8*)&Kl[(kr*64 +      l4*8) ^ ((kr&7)<<3)];
        short8 a1 = *(const short8*)&Kl[(kr*64 + 32 + l4*8) ^ ((kr&7)<<3)];
        f32x4 acc = (f32x4){0.f,0.f,0.f,0.f};
        acc = __builtin_amdgcn_mfma_f32_16x16x32_bf16(a0, bq[0], acc, 0,0,0);
        acc = __builtin_amdgcn_mfma_f32_16x16x32_bf16(a1, bq[1], acc, 0,0,0);
        s[kf] = acc;
    }

    const int qg = t0 + w*16 + l15;
    float m = -1e30f;
    #pragma unroll
    for (int kf=0;kf<8;++kf){
        #pragma unroll
        for (int j=0;j<4;++j){
            const int kg = kb0 + kf*16 + l4*4 + j;
            const int diff = qg - kg;
            const float v = (kg >= 0 && diff >= 0 && diff < 64) ? s[kf][j]*0.125f : -1e30f;
            s[kf][j] = v;
            m = fmaxf(m, v);
        }
    }
    m = fmaxf(m, __shfl_xor(m,16));
    m = fmaxf(m, __shfl_xor(m,32));
    float lsum = 0.f;
    unsigned lo[8], hi[8];
    #pragma unroll
    for (int kf=0;kf<8;++kf){
        const float p0 = expf(s[kf][0]-m), p1 = expf(s[kf][1]-m);
        const float p2 = expf(s[kf][2]-m), p3 = expf(s[kf][3]-m);
        lsum += (p0+p1)+(p2+p3);
        lo[kf] = pk2(p0,p1);
        hi[kf] = pk2(p2,p3);
    }
    lsum += __shfl_xor(lsum,16);
    lsum += __shfl_xor(lsum,32);
    const float inv = 1.f/lsum;

    f32x4 o[4];
    #pragma unroll
    for (int df=0;df<4;++df) o[df] = (f32x4){0.f,0.f,0.f,0.f};
    const int baseLane = l15 + ((l4&1)<<5);
    const bool hiHalf = (l4>>1) != 0;
    #pragma unroll
    for (int kb=0;kb<4;++kb){
        const int x0 = __shfl((int)lo[2*kb],   baseLane);
        const int x1 = __shfl((int)hi[2*kb],   baseLane);
        const int x2 = __shfl((int)lo[2*kb],   baseLane+16);
        const int x3 = __shfl((int)hi[2*kb],   baseLane+16);
        const int y0 = __shfl((int)lo[2*kb+1], baseLane);
        const int y1 = __shfl((int)hi[2*kb+1], baseLane);
        const int y2 = __shfl((int)lo[2*kb+1], baseLane+16);
        const int y3 = __shfl((int)hi[2*kb+1], baseLane+16);
        int4 afi;
        afi.x = hiHalf ? y0 : x0;
        afi.y = hiHalf ? y1 : x1;
        afi.z = hiHalf ? y2 : x2;
        afi.w = hiHalf ? y3 : x3;
        union { int4 i; short8 s; } cv; cv.i = afi;
        #pragma unroll
        for (int df=0;df<4;++df){
            const int vr = df*16 + l15;
            short8 bv = *(const short8*)&Vl[(vr*128 + kb*32 + l4*8) ^ ((vr&15)<<3)];
            o[df] = __builtin_amdgcn_mfma_f32_16x16x32_bf16(cv.s, bv, o[df], 0,0,0);
        }
    }

    #pragma unroll
    for (int j=0;j<4;++j){
        const float invj = __shfl(inv, l4*4 + j);
        const int mrow = b*T_ + t0 + w*16 + l4*4 + j;
        u16* op = MED + (size_t)mrow*D_ + h*HD_ + l15;
        #pragma unroll
        for (int df=0;df<4;++df)
            op[df*16] = bf1(o[df][j] * invj);
    }
}

// ---------------------------------------------------------------------------
// Chunked scans: p1 = per-chunk aggregate; p3 = own prefix + replay.
// ---------------------------------------------------------------------------
__global__ __launch_bounds__(256) void scan1_p1(const u16* __restrict__ QKVG,
    float* __restrict__ CA, float* __restrict__ CC)
{
    const int d = threadIdx.x, c = blockIdx.x, b = blockIdx.y;
    const u16* base = QKVG + ((size_t)(b*T_ + c*LCH))*1280;
    float sgk=0.f, sgkv=0.f;
    for (int t=0;t<LCH;++t){
        float gk = bfu(base[(size_t)t*1280 + 768 + d]);
        gk = gk > 0.f ? gk + 1.f : expf(gk);
        float gv = bfu(base[(size_t)t*1280 + 1024 + d]);
        sgk += gk; sgkv += gk*gv;
    }
    CA[((size_t)b*NC_ + c)*D_ + d] = sgk;
    CC[((size_t)b*NC_ + c)*D_ + d] = sgkv;
}

__global__ __launch_bounds__(256) void scan1_p3(const u16* __restrict__ QKVG,
    const float* __restrict__ CA, const float* __restrict__ CC, u16* __restrict__ CONC)
{
    const int d = threadIdx.x, c = blockIdx.x, b = blockIdx.y;
    float sgk = 0.f, sgkv = 0.f;
    for (int cc=0; cc<c; ++cc){
        sgk  += CA[((size_t)b*NC_ + cc)*D_ + d];
        sgkv += CC[((size_t)b*NC_ + cc)*D_ + d];
    }
    const u16* base = QKVG + ((size_t)(b*T_ + c*LCH))*1280;
    u16* out = CONC + ((size_t)(b*T_ + c*LCH))*D_ + d;
    for (int t=0;t<LCH;++t){
        float gk = bfu(base[(size_t)t*1280 + 768 + d]);
        gk = gk > 0.f ? gk + 1.f : expf(gk);
        float gv = bfu(base[(size_t)t*1280 + 1024 + d]);
        sgk += gk; sgkv += gk*gv;
        out[(size_t)t*D_] = bf1(sgkv / (sgk + 1e-5f));
    }
}

__global__ __launch_bounds__(256) void ema_p1h(const u16* __restrict__ X,
    float* __restrict__ CARRY, float alpha)
{
    const int d = threadIdx.x, c = blockIdx.x, b = blockIdx.y;
    const u16* xp = X + ((size_t)(b*T_ + c*LCH))*D_ + d;
    float g = 0.f;
    for (int t=0;t<LCH;++t) g = 0.9f*g + alpha*bfu(xp[(size_t)t*D_]);
    CARRY[((size_t)b*NC_ + c)*D_ + d] = g;
}

__global__ __launch_bounds__(256) void ema_p3h(const u16* __restrict__ X,
    const float* __restrict__ CARRY, u16* __restrict__ OUT, float alpha,
    float* __restrict__ traj)
{
    const int d = threadIdx.x, c = blockIdx.x, b = blockIdx.y;
    const float dL = powf(0.9f, (float)LCH);
    float g = 0.f;
    for (int cc=0; cc<c; ++cc) g = CARRY[((size_t)b*NC_ + cc)*D_ + d] + dL*g;
    const u16* xp = X + ((size_t)(b*T_ + c*LCH))*D_ + d;
    u16* op = OUT + ((size_t)(b*T_ + c*LCH))*D_ + d;
    for (int t=0;t<LCH;++t){
        g = 0.9f*g + alpha*bfu(xp[(size_t)t*D_]);
        op[(size_t)t*D_] = bf1(g);
    }
    if (c == NC_-1) traj[b*D_ + d] = g;
}

__global__ __launch_bounds__(256) void ema_p3_state_h(const u16* __restrict__ X,
    const float* __restrict__ CARRY, const float* __restrict__ SEQ, float* __restrict__ OUT)
{
    const int d = threadIdx.x, c = blockIdx.x, b = blockIdx.y;
    const float dL = powf(0.9f, (float)LCH);
    float a = 0.f;
    for (int cc=0; cc<c; ++cc) a = CARRY[((size_t)b*NC_ + cc)*D_ + d] + dL*a;
    const float ss = SEQ[b*D_ + d];
    float dp = powf(0.9f, (float)(c*LCH + 1));
    const u16* xp = X + ((size_t)(b*T_ + c*LCH))*D_ + d;
    float* op = OUT + ((size_t)(b*T_ + c*LCH))*D_ + d;
    for (int t=0;t<LCH;++t){
        a = 0.9f*a + bfu(xp[(size_t)t*D_]);
        op[(size_t)t*D_] = fmaf(ss, dp, a);
        dp *= 0.9f;
    }
}

// ---------------------------------------------------------------------------
// LayerNorms
// ---------------------------------------------------------------------------
__global__ __launch_bounds__(256) void ln_k(const float* __restrict__ in,
    const float* __restrict__ g, const float* __restrict__ b,
    float* __restrict__ out, u16* __restrict__ out2)
{
    int row  = blockIdx.x*4 + (threadIdx.x>>6);
    int lane = threadIdx.x & 63;
    const float* ip = in + (size_t)row*D_ + lane*4;
    float4 x = *(const float4*)ip;
    float s  = x.x+x.y+x.z+x.w;
    float s2 = x.x*x.x + x.y*x.y + x.z*x.z + x.w*x.w;
    #pragma unroll
    for (int o=1;o<64;o<<=1){ s += __shfl_xor(s,o); s2 += __shfl_xor(s2,o); }
    float mean = s * (1.f/256.f);
    float var  = s2 * (1.f/256.f) - mean*mean;
    float rs = rsqrtf(var + 1e-5f);
    int db = lane*4;
    float4 r;
    r.x=(x.x-mean)*rs*g[db+0]+b[db+0];
    r.y=(x.y-mean)*rs*g[db+1]+b[db+1];
    r.z=(x.z-mean)*rs*g[db+2]+b[db+2];
    r.w=(x.w-mean)*rs*g[db+3]+b[db+3];
    if (out)
        *(float4*)(out + (size_t)row*D_ + db) = r;
    if (out2)
        *(uint2*)(out2 + (size_t)row*D_ + db) = (uint2){ pk2(r.x,r.y), pk2(r.z,r.w) };
}

__global__ __launch_bounds__(256) void ln3_k(const float* __restrict__ in,
    const float* __restrict__ g3, const float* __restrict__ b3, u16* __restrict__ states,
    const float* __restrict__ g4, const float* __restrict__ b4, float* __restrict__ fsout)
{
    int row  = blockIdx.x*4 + (threadIdx.x>>6);
    int lane = threadIdx.x & 63;
    const float* ip = in + (size_t)row*D_ + lane*4;
    float4 x = *(const float4*)ip;
    float s  = x.x+x.y+x.z+x.w;
    float s2 = x.x*x.x + x.y*x.y + x.z*x.z + x.w*x.w;
    #pragma unroll
    for (int o=1;o<64;o<<=1){ s += __shfl_xor(s,o); s2 += __shfl_xor(s2,o); }
    float mean = s * (1.f/256.f);
    float var  = s2 * (1.f/256.f) - mean*mean;
    float rs = rsqrtf(var + 1e-5f);
    int db = lane*4;
    float4 st;
    st.x=(x.x-mean)*rs*g3[db+0]+b3[db+0];
    st.y=(x.y-mean)*rs*g3[db+1]+b3[db+1];
    st.z=(x.z-mean)*rs*g3[db+2]+b3[db+2];
    st.w=(x.w-mean)*rs*g3[db+3]+b3[db+3];
    *(uint2*)(states + (size_t)row*D_ + db) = (uint2){ pk2(st.x,st.y), pk2(st.z,st.w) };

    if ((row & (T_-1)) == T_-1){
        float u  = st.x+st.y+st.z+st.w;
        float u2 = st.x*st.x + st.y*st.y + st.z*st.z + st.w*st.w;
        #pragma unroll
        for (int o=1;o<64;o<<=1){ u += __shfl_xor(u,o); u2 += __shfl_xor(u2,o); }
        float m2 = u * (1.f/256.f);
        float v2 = u2 * (1.f/256.f) - m2*m2;
        float r2 = rsqrtf(v2 + 1e-5f);
        float4 fs;
        fs.x=(st.x-m2)*r2*g4[db+0]+b4[db+0];
        fs.y=(st.y-m2)*r2*g4[db+1]+b4[db+1];
        fs.z=(st.z-m2)*r2*g4[db+2]+b4[db+2];
        fs.w=(st.w-m2)*r2*g4[db+3]+b4[db+3];
        *(float4*)(fsout + (size_t)(row>>11)*D_ + db) = fs;
    }
}

// ---------------------------------------------------------------------------
extern "C" void kernel_launch(void* const* d_in, const int* in_sizes, int n_in,
                              void* d_out, int out_size, void* d_ws, size_t ws_size,
                              hipStream_t stream)
{
    const float* X     = (const float*)d_in[0];
    const float* SEQ   = (const float*)d_in[1];
    const float* conv_w= (const float*)d_in[3];
    const float* conv_b= (const float*)d_in[4];
    const float* qkv_w = (const float*)d_in[5];
    const float* qkv_b = (const float*)d_in[6];
    const float* mo_w  = (const float*)d_in[7];
    const float* mo_b  = (const float*)d_in[8];
    const float* fg_w  = (const float*)d_in[9];
    const float* fg_b  = (const float*)d_in[10];
    const float* gkv_w = (const float*)d_in[11];
    const float* gkv_b = (const float*)d_in[12];
    const float* go_w  = (const float*)d_in[13];
    const float* go_b  = (const float*)d_in[14];
    const float* comb_w= (const float*)d_in[15];
    const float* comb_b= (const float*)d_in[16];
    const float* ffn1_w= (const float*)d_in[17];
    const float* ffn1_b= (const float*)d_in[18];
    const float* ffn2_w= (const float*)d_in[19];
    const float* ffn2_b= (const float*)d_in[20];
    const float* tr1_w = (const float*)d_in[21];
    const float* tr1_b = (const float*)d_in[22];
    const float* tr2_w = (const float*)d_in[23];
    const float* tr2_b = (const float*)d_in[24];
    const float* p2s_w = (const float*)d_in[25];
    const float* p2s_b = (const float*)d_in[26];
    const float* s2p_w = (const float*)d_in[27];
    const float* s2p_b = (const float*)d_in[28];
    const float* ln1_g = (const float*)d_in[29];
    const float* ln1_b = (const float*)d_in[30];
    const float* ln2_g = (const float*)d_in[31];
    const float* ln2_b = (const float*)d_in[32];
    const float* ln3_g = (const float*)d_in[33];
    const float* ln3_b = (const float*)d_in[34];
    const float* ln4_g = (const float*)d_in[35];
    const float* ln4_b = (const float*)d_in[36];

    // -------- workspace carve (256-byte aligned chunks) --------
    char* p = (char*)d_ws;
    auto alloc = [&](size_t bytes)->char*{ char* r = p; p += (bytes + 255) & ~(size_t)255; return r; };

    u16*   QKVG = (u16*)  alloc((size_t)M_*1280*2);
    u16*   Wh   = (u16*)  alloc((size_t)NWELEM*2);
    float* bq   = (float*)alloc(1280*4);
    float* bcomb= (float*)alloc(256*4);
    u16*   WA   = (u16*)  alloc((size_t)512*256*2);   // tr1a + 0.3*tr1a@p2s
    u16*   WF   = (u16*)  alloc((size_t)1024*256*2);  // 0.3*ffn1@s2p
    u16*   WG   = (u16*)  alloc((size_t)256*256*2);   // combC@go
    u16*   Xh   = (u16*)  alloc((size_t)M_*256*2);
    u16*   MED  = (u16*)  alloc((size_t)M_*256*2);
    u16*   MED2 = (u16*)  alloc((size_t)M_*256*2);
    u16*   LH   = (u16*)  alloc((size_t)M_*256*2);
    u16*   CONC = (u16*)  alloc((size_t)M_*256*2);
    u16*   MOUT = (u16*)  alloc((size_t)M_*256*2);
    float* PRE1 = (float*)alloc((size_t)M_*256*4);
    u16*   PRh  = (u16*)  alloc((size_t)M_*256*2);
    u16*   GSUM = (u16*)  alloc((size_t)M_*256*2);
    u16*   H1   = (u16*)  alloc((size_t)M_*512*2);
    u16*   SCALEDh=(u16*) alloc((size_t)M_*256*2);
    float* PRE3 = (float*)alloc((size_t)M_*256*4);
    u16*   STATESh=(u16*) alloc((size_t)M_*256*2);
    u16*   H2   = (u16*)  alloc((size_t)M_*1024*2);
    float* PRE2 = (float*)alloc((size_t)M_*256*4);
    float* CAR0 = (float*)alloc((size_t)B_*NC_*D_*4);
    float* CAR1 = (float*)alloc((size_t)B_*NC_*D_*4);

    float* out_pr = (float*)d_out;
    float* out_fs = out_pr + (size_t)M_*256;
    float* out_tj = out_fs + B_*256;

    const dim3 blk256(256), blk512(512);
    const dim3 scan_grid(NC_, B_);
    const int NRg = M_/128;   // 64 row tiles

    // 0. convert weights + X to bf16 (go/p2s/s2p transposed), bias folds
    cvt_k<<<dim3(3842), blk256, 0, stream>>>(
        qkv_w, gkv_w, qkv_b, gkv_b, mo_w, fg_w, go_w, go_b, comb_w, comb_b,
        ffn1_w, ffn2_w, tr1_w, tr2_w, p2s_w, s2p_w, X, Wh, Xh, bq, bcomb);
    // 0a. WA = tr1a + 0.3*tr1a@p2s   (M=512, N=256, K=256)
    gemm_k<<<dim3(16), blk512, 0, stream>>>(
        Wh+OFF_TR1, 512, Wh+OFF_P2S, 256, 256,
        nullptr,0,nullptr,0,0,  nullptr,0,nullptr,0,0,
        nullptr, Wh+OFF_TR1, 1, 512, WA, 256, 1, OP_AXPBY, 4);
    // 0b. WF = 0.3*ffn1@s2p          (M=1024, N=256, K=256)
    gemm_k<<<dim3(32), blk512, 0, stream>>>(
        Wh+OFF_FFN1, 256, Wh+OFF_S2P, 256, 256,
        nullptr,0,nullptr,0,0,  nullptr,0,nullptr,0,0,
        nullptr, nullptr, 0, 256, WF, 256, 1, OP_SCALE03, 4);
    // 0c. WG = combC@go              (M=256, N=256, K=256)
    gemm_k<<<dim3(8), blk512, 0, stream>>>(
        Wh+OFF_COMB+512, 768, Wh+OFF_GO, 256, 256,
        nullptr,0,nullptr,0,0,  nullptr,0,nullptr,0,0,
        nullptr, nullptr, 0, 256, WG, 256, 1, OP_NONE, 4);
    // 1. fused qkv+gkv projection -> QKVG (bf16)
    gemm_k<<<dim3(NRg*20), blk512, 0, stream>>>(
        Xh, 256, Wh+OFF_QKV, 256, 256,
        nullptr,0,nullptr,0,0,  nullptr,0,nullptr,0,0,
        bq, nullptr, 0, 256, QKVG, 1280, 1, OP_NONE, 20);
    // 2. local_history (depthwise conv) -> LH bf16
    conv_k<<<dim3(M_*D_/1024), blk256, 0, stream>>>(Xh, conv_w, conv_b, LH);
    // 3. banded attention -> MED bf16
    attn_k<<<dim3(T_/64, H_, B_), blk256, 0, stream>>>(QKVG, MED);
    // 4. mo projection -> MED2 bf16
    gemm_k<<<dim3(NRg*4), blk512, 0, stream>>>(
        MED, 256, Wh+OFF_MO, 256, 256,
        nullptr,0,nullptr,0,0,  nullptr,0,nullptr,0,0,
        mo_b, nullptr, 0, 256, MED2, 256, 1, OP_NONE, 4);
    // 5. concepts scan -> CONC bf16
    scan1_p1<<<scan_grid, blk256, 0, stream>>>(QKVG, CAR0, CAR1);
    scan1_p3<<<scan_grid, blk256, 0, stream>>>(QKVG, CAR0, CAR1, CONC);
    // 6. medium_out = MED2 * sigmoid([X,MED2]@fg^T + b) -> MOUT bf16
    gemm_k<<<dim3(NRg*4), blk512, 0, stream>>>(
        Xh, 256, Wh+OFF_FG, 512, 256,
        MED2, 256, Wh+OFF_FG+256, 512, 256,  nullptr,0,nullptr,0,0,
        fg_b, MED2, 1, 256, MOUT, 256, 1, OP_SIGMUL, 4);
    // 7. pre_ln1 = X + LH@combA + MOUT@combB + CONC@WG + bcomb -> PRE1 fp32
    //    (go folded into WG, go_b folded into bcomb)
    gemm_k<<<dim3(NRg*4), blk512, 0, stream>>>(
        LH, 256, Wh+OFF_COMB, 768, 256,
        MOUT, 256, Wh+OFF_COMB+256, 768, 256,
        CONC, 256, WG, 256, 256,
        bcomb, X, 0, 256, PRE1, 256, 0, OP_ADDAUX, 4);
    // 8. pr = LN1 -> PRh bf16
    ln_k<<<dim3(M_/4), blk256, 0, stream>>>(PRE1, ln1_g, ln1_b, nullptr, PRh);
    // 9. global_summary EMA -> GSUM bf16 + traj
    ema_p1h<<<scan_grid, blk256, 0, stream>>>(PRh, CAR0, 0.1f);
    ema_p3h<<<scan_grid, blk256, 0, stream>>>(PRh, CAR0, GSUM, 0.1f, out_tj);
    // 10. H1 = gelu(pr@WA^T + gsum@tr1b^T + b)   (p2s folded into WA)
    gemm_k<<<dim3(NRg*8), blk512, 0, stream>>>(
        PRh, 256, WA, 256, 256,
        GSUM, 256, Wh+OFF_TR1+256, 512, 256,  nullptr,0,nullptr,0,0,
        tr1_b, nullptr, 0, 256, H1, 512, 1, OP_GELU, 8);
    // 11. scaled = 0.5*tanh(H1@tr2^T + b) -> SCALEDh bf16
    gemm_k<<<dim3(NRg*4), blk512, 0, stream>>>(
        H1, 512, Wh+OFF_TR2, 512, 512,
        nullptr,0,nullptr,0,0,  nullptr,0,nullptr,0,0,
        tr2_b, nullptr, 0, 256, SCALEDh, 256, 1, OP_TANHHALF, 4);
    // 12. state EMA + decayed initial -> PRE3 fp32
    ema_p1h<<<scan_grid, blk256, 0, stream>>>(SCALEDh, CAR0, 1.0f);
    ema_p3_state_h<<<scan_grid, blk256, 0, stream>>>(SCALEDh, CAR0, SEQ, PRE3);
    // 13. states = LN3 -> STATESh bf16; final_state = LN4(states[-1]) -> out
    ln3_k<<<dim3(M_/4), blk256, 0, stream>>>(PRE3, ln3_g, ln3_b, STATESh, ln4_g, ln4_b, out_fs);
    // 14. H2 = gelu(pr@ffn1^T + states@WF^T + b)  (s2p folded into WF)
    gemm_k<<<dim3(NRg*16), blk512, 0, stream>>>(
        PRh, 256, Wh+OFF_FFN1, 256, 256,
        STATESh, 256, WF, 256, 256,  nullptr,0,nullptr,0,0,
        ffn1_b, nullptr, 0, 256, H2, 1024, 1, OP_GELU, 16);
    // 15. pre_ln2 = pr + H2@ffn2^T + b -> PRE2 fp32
    gemm_k<<<dim3(NRg*4), blk512, 0, stream>>>(
        H2, 1024, Wh+OFF_FFN2, 1024, 1024,
        nullptr,0,nullptr,0,0,  nullptr,0,nullptr,0,0,
        ffn2_b, PRh, 1, 256, PRE2, 256, 0, OP_ADDAUX, 4);
    // 16. pr_out = LN2 -> d_out
    ln_k<<<dim3(M_/4), blk256, 0, stream>>>(PRE2, ln2_g, ln2_b, out_pr, nullptr);
}

// Round 12
// 253.371 us; speedup vs baseline: 1.4379x; 1.0890x over previous
//
#include <hip/hip_runtime.h>
#include <hip/hip_bf16.h>
#include <math.h>

#define D_  256
#define T_  2048
#define B_  4
#define M_  (B_*T_)
#define H_  4
#define HD_ 64

#define NC_ 64          // scan chunks
#define LCH (T_/NC_)    // 32 steps per chunk

enum { OP_NONE=0, OP_SIGMUL=1, OP_ADDAUX=2, OP_AXPBY=3, OP_GELU=4, OP_TANHHALF=5 };

typedef unsigned short u16;
typedef short short8 __attribute__((ext_vector_type(8)));
typedef float f32x4  __attribute__((ext_vector_type(4)));

__device__ __forceinline__ float gelu_f(float x){ return 0.5f*x*(1.0f+erff(x*0.70710678118654752f)); }
__device__ __forceinline__ float sigmoid_f(float x){ return 1.0f/(1.0f+expf(-x)); }

__device__ __forceinline__ unsigned pk2(float a, float b){
    __hip_bfloat162 h = __float22bfloat162_rn(make_float2(a,b));
    union { __hip_bfloat162 h; unsigned u; } c; c.h = h; return c.u;
}
__device__ __forceinline__ float bfu(u16 u){ return __uint_as_float(((unsigned)u)<<16); }
__device__ __forceinline__ u16 bf1(float x){ return (u16)(pk2(x,x)&0xffffu); }

// weight-pack element offsets inside Wh (u16 elements)
#define OFF_QKV   0u        // fused qkv(768)+gkv(512) rows -> [1280,256]
#define OFF_MO    327680u
#define OFF_FG    393216u
#define OFF_GO    524288u
#define OFF_COMB  589824u
#define OFF_FFN1  786432u
#define OFF_FFN2  1048576u
#define OFF_TR1   1310720u
#define OFF_TR2   1572864u
#define OFF_P2S   1703936u
#define OFF_S2P   1769472u
#define NWELEM    1835008u
#define NXELEM    2097152u
#define CVT_BLKS  3842u
#define CONV_BLKS 2048u

// ---------------------------------------------------------------------------
// fp32 -> bf16 conversion of all weights + X, qkv/gkv bias concat, AND the
// depthwise causal conv (K=8) fused as a second block range (reads fp32 X).
// ---------------------------------------------------------------------------
__global__ __launch_bounds__(256) void cvt_conv_k(
    const float* __restrict__ qkv_w, const float* __restrict__ gkv_w,
    const float* __restrict__ qkv_b, const float* __restrict__ gkv_b,
    const float* __restrict__ mo_w,  const float* __restrict__ fg_w,
    const float* __restrict__ go_w,  const float* __restrict__ comb_w,
    const float* __restrict__ ffn1_w,const float* __restrict__ ffn2_w,
    const float* __restrict__ tr1_w, const float* __restrict__ tr2_w,
    const float* __restrict__ p2s_w, const float* __restrict__ s2p_w,
    const float* __restrict__ X,
    const float* __restrict__ conv_w, const float* __restrict__ conv_b,
    u16* __restrict__ Wh, u16* __restrict__ Xh, float* __restrict__ bq,
    u16* __restrict__ LH)
{
    if (blockIdx.x >= CVT_BLKS){
        // ---- depthwise causal conv: 4 d's per thread, fp32 X in, bf16 out
        int idx = (blockIdx.x - CVT_BLKS)*256 + threadIdx.x;   // over M*D/4
        int d4 = (idx & 63) * 4;
        int bt = idx >> 6;
        int t = bt & (T_-1);
        float a0 = conv_b[d4], a1 = conv_b[d4+1], a2 = conv_b[d4+2], a3 = conv_b[d4+3];
        const float* xp = X + (size_t)bt*D_ + d4;
        #pragma unroll
        for (int j=0;j<8;++j){
            int tt = t - 7 + j;
            if (tt >= 0){
                float4 v = *(const float4*)(xp + (size_t)(j-7)*D_);
                a0 += v.x * conv_w[(d4+0)*8 + j];
                a1 += v.y * conv_w[(d4+1)*8 + j];
                a2 += v.z * conv_w[(d4+2)*8 + j];
                a3 += v.w * conv_w[(d4+3)*8 + j];
            }
        }
        *(uint2*)(LH + (size_t)bt*D_ + d4) = (uint2){ pk2(a0,a1), pk2(a2,a3) };
        return;
    }
    size_t i = ((size_t)blockIdx.x*256 + threadIdx.x)*4;
    if (i < NWELEM){
        const float* s; size_t base;
        if      (i < OFF_MO)  { s=(i<196608)?qkv_w:gkv_w; base=(i<196608)?0:196608; }
        else if (i < OFF_FG)  { s=mo_w;   base=OFF_MO; }
        else if (i < OFF_GO)  { s=fg_w;   base=OFF_FG; }
        else if (i < OFF_COMB){ s=go_w;   base=OFF_GO; }
        else if (i < OFF_FFN1){ s=comb_w; base=OFF_COMB; }
        else if (i < OFF_FFN2){ s=ffn1_w; base=OFF_FFN1; }
        else if (i < OFF_TR1) { s=ffn2_w; base=OFF_FFN2; }
        else if (i < OFF_TR2) { s=tr1_w;  base=OFF_TR1; }
        else if (i < OFF_P2S) { s=tr2_w;  base=OFF_TR2; }
        else if (i < OFF_S2P) { s=p2s_w;  base=OFF_P2S; }
        else                  { s=s2p_w;  base=OFF_S2P; }
        float4 v = *(const float4*)(s + (i-base));
        *(uint2*)(Wh + i) = (uint2){ pk2(v.x,v.y), pk2(v.z,v.w) };
    } else if (i < NWELEM + NXELEM){
        size_t j = i - NWELEM;
        float4 v = *(const float4*)(X + j);
        *(uint2*)(Xh + j) = (uint2){ pk2(v.x,v.y), pk2(v.z,v.w) };
    } else if (i < NWELEM + NXELEM + 1280){
        size_t j = i - (NWELEM + NXELEM);
        #pragma unroll
        for (int k=0;k<4;++k){
            size_t e = j + k;
            bq[e] = (e < 768) ? qkv_b[e] : gkv_b[e-768];
        }
    }
}

// ---------------------------------------------------------------------------
// bf16 MFMA GEMM, register-staged pipeline, tile 128x64, BK=64,
// 512 threads = 8 waves (4M x 2N), mfma_f32_16x16x32_bf16, XCD swizzle.
// (proven r9 structure, byte-identical inner loop)
// ---------------------------------------------------------------------------
__global__ __launch_bounds__(512) void gemm_k(
    const u16* __restrict__ A0, const u16* __restrict__ W0, int ldw0, int K0,
    const u16* __restrict__ A1, const u16* __restrict__ W1, int ldw1, int K1,
    const u16* __restrict__ A2, const u16* __restrict__ W2, int ldw2, int K2,
    const float* __restrict__ bias, const void* __restrict__ aux, int aux_bf16,
    void* __restrict__ C, int ldc, int c_bf16, int op, int ncol)
{
    __shared__ u16 As[128*64];
    __shared__ u16 Ws[64*64];

    const int q8   = gridDim.x >> 3;
    const int lid  = (blockIdx.x & 7)*q8 + (blockIdx.x >> 3);
    const int brow = lid / ncol;
    const int bcol = lid - brow*ncol;
    const int row0 = brow*128, col0 = bcol*64;

    const int tid  = threadIdx.x;
    const int lane = tid & 63, wid = tid >> 6;
    const int wm = (wid >> 1)*32, wn = (wid & 1)*32;
    const int l15 = lane & 15, l4 = lane >> 4;
    const int rowA = tid >> 2;            // 0..127
    const int scA  = (tid & 3) * 8;
    const int rowW = tid >> 3;            // 0..63
    const int scW  = (tid & 7) * 8;

    f32x4 acc[2][2];
    #pragma unroll
    for (int i=0;i<2;++i)
        #pragma unroll
        for (int j=0;j<2;++j) acc[i][j] = (f32x4){0.f,0.f,0.f,0.f};

    uint4 ra0, ra1, rw0;

    auto loadtile = [&](const u16* A, const u16* W, int ldw, int K, int kb){
        const u16* ga = A + (size_t)(row0+rowA)*K + kb + scA;
        ra0 = *(const uint4*)ga;
        ra1 = *(const uint4*)(ga + 32);
        rw0 = *(const uint4*)(W + (size_t)(col0+rowW)*ldw + kb + scW);
    };
    auto storetile = [&](){
        const int sw = (rowA&7)<<3;
        *(uint4*)&As[(rowA*64 + scA) ^ sw]      = ra0;
        *(uint4*)&As[(rowA*64 + scA + 32) ^ sw] = ra1;
        *(uint4*)&Ws[(rowW*64 + scW) ^ ((rowW&7)<<3)] = rw0;
    };
    auto mfma_tile = [&](){
        #pragma unroll
        for (int ks=0;ks<2;++ks){
            const int koff = ks*32 + l4*8;
            short8 af[2], bf[2];
            #pragma unroll
            for (int f=0;f<2;++f){
                const int ar = wm + f*16 + l15;
                af[f] = *(const short8*)&As[(ar*64 + koff) ^ ((ar&7)<<3)];
                const int brn = wn + f*16 + l15;
                bf[f] = *(const short8*)&Ws[(brn*64 + koff) ^ ((brn&7)<<3)];
            }
            #pragma unroll
            for (int fm=0;fm<2;++fm)
                #pragma unroll
                for (int fn=0;fn<2;++fn)
                    acc[fm][fn] = __builtin_amdgcn_mfma_f32_16x16x32_bf16(
                        af[fm], bf[fn], acc[fm][fn], 0, 0, 0);
        }
    };

    const u16* Ac = A0; const u16* Wc = W0; int ldwc = ldw0, Kc = K0, kb = 0;
    loadtile(Ac, Wc, ldwc, Kc, 0);
    while (true){
        __syncthreads();            // prev MFMA done; LDS free
        storetile();
        __syncthreads();            // staged tile visible
        int nkb = kb + 64;
        const u16* nA = Ac; const u16* nW = Wc; int nld = ldwc, nK = Kc;
        bool have_next = true;
        if (nkb >= Kc){
            if (Ac == A0 && A1){ nA = A1; nW = W1; nld = ldw1; nK = K1; nkb = 0; }
            else if (Ac == A1 && A2){ nA = A2; nW = W2; nld = ldw2; nK = K2; nkb = 0; }
            else have_next = false;
        }
        if (have_next) loadtile(nA, nW, nld, nK, nkb);   // in flight across MFMA
        mfma_tile();
        if (!have_next) break;
        Ac = nA; Wc = nW; ldwc = nld; Kc = nK; kb = nkb;
    }

    #pragma unroll
    for (int fn=0;fn<2;++fn){
        const int n = col0 + wn + fn*16 + l15;
        const float bv = bias[n];
        #pragma unroll
        for (int fm=0;fm<2;++fm){
            #pragma unroll
            for (int j=0;j<4;++j){
                const int m = row0 + wm + fm*16 + l4*4 + j;
                float v = acc[fm][fn][j] + bv;
                if (op==OP_GELU)          v = gelu_f(v);
                else if (op==OP_TANHHALF) v = 0.5f*tanhf(v);
                else if (op!=OP_NONE){
                    const size_t ai = (size_t)m*D_ + n;
                    const float a = aux_bf16 ? bfu(((const u16*)aux)[ai])
                                             : ((const float*)aux)[ai];
                    if (op==OP_SIGMUL)      v = a*sigmoid_f(v);
                    else if (op==OP_ADDAUX) v = v + a;
                    else                    v = a + 0.3f*v;
                }
                if (c_bf16) ((u16*)C)[(size_t)m*ldc + n] = bf1(v);
                else        ((float*)C)[(size_t)m*ldc + n] = v;
            }
        }
    }
}

// ---------------------------------------------------------------------------
// MFMA banded attention. Per block: (b, h, 64-query tile), 4 waves.
// ---------------------------------------------------------------------------
__global__ __launch_bounds__(256) void attn_k(const u16* __restrict__ QKVG,
    u16* __restrict__ MED)
{
    __shared__ u16 Kl[128*64];
    __shared__ u16 Ql[64*64];
    __shared__ u16 Vl[64*128];
    const int b = blockIdx.z, h = blockIdx.y;
    const int t0 = blockIdx.x * 64;
    const int kb0 = t0 - 64;
    const int tid = threadIdx.x;

    {
        const int r0 = tid >> 3, c8 = (tid & 7) * 8;
        #pragma unroll
        for (int rep=0;rep<4;++rep){
            const int r = r0 + rep*32;
            const int kg = kb0 + r;
            uint4 pk = {0,0,0,0}, pv = {0,0,0,0};
            if (kg >= 0){
                const u16* gp = QKVG + ((size_t)(b*T_ + kg))*1280 + h*HD_ + c8;
                pk = *(const uint4*)(gp + 256);
                pv = *(const uint4*)(gp + 512);
            }
            *(uint4*)&Kl[(r*64 + c8) ^ ((r&7)<<3)] = pk;
            const u16* pvu = (const u16*)&pv;
            #pragma unroll
            for (int j=0;j<8;++j){
                const int d = c8 + j;
                Vl[(d*128 + r) ^ ((d&15)<<3)] = pvu[j];
            }
        }
        #pragma unroll
        for (int rep=0;rep<2;++rep){
            const int r = r0 + rep*32;
            uint4 pq = *(const uint4*)(QKVG + ((size_t)(b*T_ + t0 + r))*1280 + h*HD_ + c8);
            *(uint4*)&Ql[(r*64 + c8) ^ ((r&7)<<3)] = pq;
        }
    }
    __syncthreads();

    const int lane = tid & 63, w = tid >> 6;
    const int l15 = lane & 15, l4 = lane >> 4;

    short8 bq[2];
    {
        const int qr = w*16 + l15;
        bq[0] = *(const short8*)&Ql[(qr*64 +      l4*8) ^ ((qr&7)<<3)];
        bq[1] = *(const short8*)&Ql[(qr*64 + 32 + l4*8) ^ ((qr&7)<<3)];
    }

    f32x4 s[8];
    #pragma unroll
    for (int kf=0;kf<8;++kf){
        const int kr = kf*16 + l15;
        short8 a0 = *(const short8*)&Kl[(kr*64 +      l4*8) ^ ((kr&7)<<3)];
        short8 a1 = *(const short8*)&Kl[(kr*64 + 32 + l4*8) ^ ((kr&7)<<3)];
        f32x4 acc = (f32x4){0.f,0.f,0.f,0.f};
        acc = __builtin_amdgcn_mfma_f32_16x16x32_bf16(a0, bq[0], acc, 0,0,0);
        acc = __builtin_amdgcn_mfma_f32_16x16x32_bf16(a1, bq[1], acc, 0,0,0);
        s[kf] = acc;
    }

    const int qg = t0 + w*16 + l15;
    float m = -1e30f;
    #pragma unroll
    for (int kf=0;kf<8;++kf){
        #pragma unroll
        for (int j=0;j<4;++j){
            const int kg = kb0 + kf*16 + l4*4 + j;
            const int diff = qg - kg;
            const float v = (kg >= 0 && diff >= 0 && diff < 64) ? s[kf][j]*0.125f : -1e30f;
            s[kf][j] = v;
            m = fmaxf(m, v);
        }
    }
    m = fmaxf(m, __shfl_xor(m,16));
    m = fmaxf(m, __shfl_xor(m,32));
    float lsum = 0.f;
    unsigned lo[8], hi[8];
    #pragma unroll
    for (int kf=0;kf<8;++kf){
        const float p0 = expf(s[kf][0]-m), p1 = expf(s[kf][1]-m);
        const float p2 = expf(s[kf][2]-m), p3 = expf(s[kf][3]-m);
        lsum += (p0+p1)+(p2+p3);
        lo[kf] = pk2(p0,p1);
        hi[kf] = pk2(p2,p3);
    }
    lsum += __shfl_xor(lsum,16);
    lsum += __shfl_xor(lsum,32);
    const float inv = 1.f/lsum;

    f32x4 o[4];
    #pragma unroll
    for (int df=0;df<4;++df) o[df] = (f32x4){0.f,0.f,0.f,0.f};
    const int baseLane = l15 + ((l4&1)<<5);
    const bool hiHalf = (l4>>1) != 0;
    #pragma unroll
    for (int kb=0;kb<4;++kb){
        const int x0 = __shfl((int)lo[2*kb],   baseLane);
        const int x1 = __shfl((int)hi[2*kb],   baseLane);
        const int x2 = __shfl((int)lo[2*kb],   baseLane+16);
        const int x3 = __shfl((int)hi[2*kb],   baseLane+16);
        const int y0 = __shfl((int)lo[2*kb+1], baseLane);
        const int y1 = __shfl((int)hi[2*kb+1], baseLane);
        const int y2 = __shfl((int)lo[2*kb+1], baseLane+16);
        const int y3 = __shfl((int)hi[2*kb+1], baseLane+16);
        int4 afi;
        afi.x = hiHalf ? y0 : x0;
        afi.y = hiHalf ? y1 : x1;
        afi.z = hiHalf ? y2 : x2;
        afi.w = hiHalf ? y3 : x3;
        union { int4 i; short8 s; } cv; cv.i = afi;
        #pragma unroll
        for (int df=0;df<4;++df){
            const int vr = df*16 + l15;
            short8 bv = *(const short8*)&Vl[(vr*128 + kb*32 + l4*8) ^ ((vr&15)<<3)];
            o[df] = __builtin_amdgcn_mfma_f32_16x16x32_bf16(cv.s, bv, o[df], 0,0,0);
        }
    }

    #pragma unroll
    for (int j=0;j<4;++j){
        const float invj = __shfl(inv, l4*4 + j);
        const int mrow = b*T_ + t0 + w*16 + l4*4 + j;
        u16* op = MED + (size_t)mrow*D_ + h*HD_ + l15;
        #pragma unroll
        for (int df=0;df<4;++df)
            op[df*16] = bf1(o[df][j] * invj);
    }
}

// ---------------------------------------------------------------------------
// Chunked scans (two-dispatch form, proven).
// ---------------------------------------------------------------------------
__global__ __launch_bounds__(256) void scan1_p1(const u16* __restrict__ QKVG,
    float* __restrict__ CA, float* __restrict__ CC)
{
    const int d = threadIdx.x, c = blockIdx.x, b = blockIdx.y;
    const u16* base = QKVG + ((size_t)(b*T_ + c*LCH))*1280;
    float sgk=0.f, sgkv=0.f;
    for (int t=0;t<LCH;++t){
        float gk = bfu(base[(size_t)t*1280 + 768 + d]);
        gk = gk > 0.f ? gk + 1.f : expf(gk);
        float gv = bfu(base[(size_t)t*1280 + 1024 + d]);
        sgk += gk; sgkv += gk*gv;
    }
    CA[((size_t)b*NC_ + c)*D_ + d] = sgk;
    CC[((size_t)b*NC_ + c)*D_ + d] = sgkv;
}

__global__ __launch_bounds__(256) void scan1_p3(const u16* __restrict__ QKVG,
    const float* __restrict__ CA, const float* __restrict__ CC, u16* __restrict__ CONC)
{
    const int d = threadIdx.x, c = blockIdx.x, b = blockIdx.y;
    float sgk = 0.f, sgkv = 0.f;
    for (int cc=0; cc<c; ++cc){
        sgk  += CA[((size_t)b*NC_ + cc)*D_ + d];
        sgkv += CC[((size_t)b*NC_ + cc)*D_ + d];
    }
    const u16* base = QKVG + ((size_t)(b*T_ + c*LCH))*1280;
    u16* out = CONC + ((size_t)(b*T_ + c*LCH))*D_ + d;
    for (int t=0;t<LCH;++t){
        float gk = bfu(base[(size_t)t*1280 + 768 + d]);
        gk = gk > 0.f ? gk + 1.f : expf(gk);
        float gv = bfu(base[(size_t)t*1280 + 1024 + d]);
        sgk += gk; sgkv += gk*gv;
        out[(size_t)t*D_] = bf1(sgkv / (sgk + 1e-5f));
    }
}

__global__ __launch_bounds__(256) void ema_p1h(const u16* __restrict__ X,
    float* __restrict__ CARRY, float alpha)
{
    const int d = threadIdx.x, c = blockIdx.x, b = blockIdx.y;
    const u16* xp = X + ((size_t)(b*T_ + c*LCH))*D_ + d;
    float g = 0.f;
    for (int t=0;t<LCH;++t) g = 0.9f*g + alpha*bfu(xp[(size_t)t*D_]);
    CARRY[((size_t)b*NC_ + c)*D_ + d] = g;
}

__global__ __launch_bounds__(256) void ema_p3h(const u16* __restrict__ X,
    const float* __restrict__ CARRY, u16* __restrict__ OUT, float alpha,
    float* __restrict__ traj)
{
    const int d = threadIdx.x, c = blockIdx.x, b = blockIdx.y;
    const float dL = powf(0.9f, (float)LCH);
    float g = 0.f;
    for (int cc=0; cc<c; ++cc) g = CARRY[((size_t)b*NC_ + cc)*D_ + d] + dL*g;
    const u16* xp = X + ((size_t)(b*T_ + c*LCH))*D_ + d;
    u16* op = OUT + ((size_t)(b*T_ + c*LCH))*D_ + d;
    for (int t=0;t<LCH;++t){
        g = 0.9f*g + alpha*bfu(xp[(size_t)t*D_]);
        op[(size_t)t*D_] = bf1(g);
    }
    if (c == NC_-1) traj[b*D_ + d] = g;
}

// ---------------------------------------------------------------------------
// Fused LN1 + gsum-EMA chunk aggregate. Block = (chunk c, batch b): 32 rows.
// Warp w handles rows it*4+w; EMA aggregate via weighted sum (order-free).
// ---------------------------------------------------------------------------
__global__ __launch_bounds__(256) void ln1ema_k(const u16* __restrict__ in,
    const float* __restrict__ g, const float* __restrict__ b,
    u16* __restrict__ out, float* __restrict__ CARRY)
{
    __shared__ float wacc[4][256];
    const int c = blockIdx.x, bb = blockIdx.y;
    const int w = threadIdx.x >> 6, lane = threadIdx.x & 63;
    const int db = lane*4;
    const int row0 = bb*T_ + c*LCH;
    float acc0=0.f, acc1=0.f, acc2=0.f, acc3=0.f;
    #pragma unroll
    for (int it=0; it<8; ++it){
        const int r = it*4 + w;
        uint2 u = *(const uint2*)(in + (size_t)(row0 + r)*D_ + db);
        float x0=bfu((u16)(u.x&0xffff)), x1=bfu((u16)(u.x>>16));
        float x2=bfu((u16)(u.y&0xffff)), x3=bfu((u16)(u.y>>16));
        float s  = x0+x1+x2+x3;
        float s2 = x0*x0+x1*x1+x2*x2+x3*x3;
        #pragma unroll
        for (int o=1;o<64;o<<=1){ s += __shfl_xor(s,o); s2 += __shfl_xor(s2,o); }
        float mean = s*(1.f/256.f);
        float var  = s2*(1.f/256.f) - mean*mean;
        float rs = rsqrtf(var + 1e-5f);
        float y0=(x0-mean)*rs*g[db+0]+b[db+0];
        float y1=(x1-mean)*rs*g[db+1]+b[db+1];
        float y2=(x2-mean)*rs*g[db+2]+b[db+2];
        float y3=(x3-mean)*rs*g[db+3]+b[db+3];
        *(uint2*)(out + (size_t)(row0+r)*D_ + db) = (uint2){ pk2(y0,y1), pk2(y2,y3) };
        const float wt = 0.1f*powf(0.9f, (float)(31-r));
        acc0 += wt*y0; acc1 += wt*y1; acc2 += wt*y2; acc3 += wt*y3;
    }
    wacc[w][db+0]=acc0; wacc[w][db+1]=acc1; wacc[w][db+2]=acc2; wacc[w][db+3]=acc3;
    __syncthreads();
    const int d = threadIdx.x;
    CARRY[((size_t)bb*NC_ + c)*D_ + d] =
        wacc[0][d] + wacc[1][d] + wacc[2][d] + wacc[3][d];
}

// ---------------------------------------------------------------------------
// Fused state-EMA replay + LN3 (+LN4 on the final row). Block = (chunk, b).
// Values staged in 32KB LDS; 8-thread row reductions; PRE3 never hits HBM.
// ---------------------------------------------------------------------------
__global__ __launch_bounds__(256) void ema_ln3_k(const u16* __restrict__ X,
    const float* __restrict__ CARRY, const float* __restrict__ SEQ,
    const float* __restrict__ g3, const float* __restrict__ b3, u16* __restrict__ states,
    const float* __restrict__ g4, const float* __restrict__ b4, float* __restrict__ fsout)
{
    __shared__ float vals[LCH][256];
    __shared__ float mv[LCH][2];
    __shared__ float st4[256];
    __shared__ float red[8];
    const int d = threadIdx.x, c = blockIdx.x, bb = blockIdx.y;
    const float dL = powf(0.9f, (float)LCH);
    float a = 0.f;
    for (int cc=0; cc<c; ++cc) a = CARRY[((size_t)bb*NC_ + cc)*D_ + d] + dL*a;
    const float ss = SEQ[bb*D_ + d];
    float dp = powf(0.9f, (float)(c*LCH + 1));
    const u16* xp = X + ((size_t)(bb*T_ + c*LCH))*D_ + d;
    for (int t=0;t<LCH;++t){
        a = 0.9f*a + bfu(xp[(size_t)t*D_]);
        vals[t][d] = fmaf(ss, dp, a);
        dp *= 0.9f;
    }
    __syncthreads();
    {
        const int r = threadIdx.x >> 3, seg = threadIdx.x & 7;
        float s=0.f, s2=0.f;
        #pragma unroll
        for (int j=0;j<32;++j){ float v = vals[r][seg*32+j]; s += v; s2 += v*v; }
        s += __shfl_xor(s,1); s2 += __shfl_xor(s2,1);
        s += __shfl_xor(s,2); s2 += __shfl_xor(s2,2);
        s += __shfl_xor(s,4); s2 += __shfl_xor(s2,4);
        if (seg == 0){
            float mean = s*(1.f/256.f);
            float var  = s2*(1.f/256.f) - mean*mean;
            mv[r][0] = mean; mv[r][1] = rsqrtf(var + 1e-5f);
        }
    }
    __syncthreads();
    const float gd = g3[d], bd = b3[d];
    const bool isLast = (c == NC_-1);
    u16* sp = states + ((size_t)(bb*T_ + c*LCH))*D_ + d;
    for (int t=0;t<LCH;++t){
        float st = (vals[t][d] - mv[t][0])*mv[t][1]*gd + bd;
        sp[(size_t)t*D_] = bf1(st);
        if (isLast && t == LCH-1) st4[d] = st;
    }
    if (isLast){
        __syncthreads();
        float v = st4[d];
        float s = v, s2 = v*v;
        #pragma unroll
        for (int o=1;o<64;o<<=1){ s += __shfl_xor(s,o); s2 += __shfl_xor(s2,o); }
        if ((threadIdx.x & 63) == 0){ red[threadIdx.x>>6] = s; red[4+(threadIdx.x>>6)] = s2; }
        __syncthreads();
        float S  = red[0]+red[1]+red[2]+red[3];
        float S2 = red[4]+red[5]+red[6]+red[7];
        float m2 = S*(1.f/256.f);
        float r2 = rsqrtf(S2*(1.f/256.f) - m2*m2 + 1e-5f);
        fsout[bb*D_ + d] = (st4[d]-m2)*r2*g4[d] + b4[d];
    }
}

// ---------------------------------------------------------------------------
// LN2: bf16 in, fp32 out (final pr_out).
// ---------------------------------------------------------------------------
__global__ __launch_bounds__(256) void ln2h_k(const u16* __restrict__ in,
    const float* __restrict__ g, const float* __restrict__ b, float* __restrict__ out)
{
    int row  = blockIdx.x*4 + (threadIdx.x>>6);
    int lane = threadIdx.x & 63;
    uint2 u = *(const uint2*)(in + (size_t)row*D_ + lane*4);
    float x0=bfu((u16)(u.x&0xffff)), x1=bfu((u16)(u.x>>16));
    float x2=bfu((u16)(u.y&0xffff)), x3=bfu((u16)(u.y>>16));
    float s  = x0+x1+x2+x3;
    float s2 = x0*x0+x1*x1+x2*x2+x3*x3;
    #pragma unroll
    for (int o=1;o<64;o<<=1){ s += __shfl_xor(s,o); s2 += __shfl_xor(s2,o); }
    float mean = s * (1.f/256.f);
    float var  = s2 * (1.f/256.f) - mean*mean;
    float rs = rsqrtf(var + 1e-5f);
    int db = lane*4;
    float4 r;
    r.x=(x0-mean)*rs*g[db+0]+b[db+0];
    r.y=(x1-mean)*rs*g[db+1]+b[db+1];
    r.z=(x2-mean)*rs*g[db+2]+b[db+2];
    r.w=(x3-mean)*rs*g[db+3]+b[db+3];
    *(float4*)(out + (size_t)row*D_ + db) = r;
}

// ---------------------------------------------------------------------------
extern "C" void kernel_launch(void* const* d_in, const int* in_sizes, int n_in,
                              void* d_out, int out_size, void* d_ws, size_t ws_size,
                              hipStream_t stream)
{
    const float* X     = (const float*)d_in[0];
    const float* SEQ   = (const float*)d_in[1];
    const float* conv_w= (const float*)d_in[3];
    const float* conv_b= (const float*)d_in[4];
    const float* qkv_w = (const float*)d_in[5];
    const float* qkv_b = (const float*)d_in[6];
    const float* mo_w  = (const float*)d_in[7];
    const float* mo_b  = (const float*)d_in[8];
    const float* fg_w  = (const float*)d_in[9];
    const float* fg_b  = (const float*)d_in[10];
    const float* gkv_w = (const float*)d_in[11];
    const float* gkv_b = (const float*)d_in[12];
    const float* go_w  = (const float*)d_in[13];
    const float* go_b  = (const float*)d_in[14];
    const float* comb_w= (const float*)d_in[15];
    const float* comb_b= (const float*)d_in[16];
    const float* ffn1_w= (const float*)d_in[17];
    const float* ffn1_b= (const float*)d_in[18];
    const float* ffn2_w= (const float*)d_in[19];
    const float* ffn2_b= (const float*)d_in[20];
    const float* tr1_w = (const float*)d_in[21];
    const float* tr1_b = (const float*)d_in[22];
    const float* tr2_w = (const float*)d_in[23];
    const float* tr2_b = (const float*)d_in[24];
    const float* p2s_w = (const float*)d_in[25];
    const float* p2s_b = (const float*)d_in[26];
    const float* s2p_w = (const float*)d_in[27];
    const float* s2p_b = (const float*)d_in[28];
    const float* ln1_g = (const float*)d_in[29];
    const float* ln1_b = (const float*)d_in[30];
    const float* ln2_g = (const float*)d_in[31];
    const float* ln2_b = (const float*)d_in[32];
    const float* ln3_g = (const float*)d_in[33];
    const float* ln3_b = (const float*)d_in[34];
    const float* ln4_g = (const float*)d_in[35];
    const float* ln4_b = (const float*)d_in[36];

    // -------- workspace carve (256-byte aligned chunks) --------
    char* p = (char*)d_ws;
    auto alloc = [&](size_t bytes)->char*{ char* r = p; p += (bytes + 255) & ~(size_t)255; return r; };

    u16*   QKVG = (u16*)  alloc((size_t)M_*1280*2);
    u16*   Wh   = (u16*)  alloc((size_t)NWELEM*2);
    float* bq   = (float*)alloc(1280*4);
    u16*   Xh   = (u16*)  alloc((size_t)M_*256*2);
    u16*   MED  = (u16*)  alloc((size_t)M_*256*2);
    u16*   MED2 = (u16*)  alloc((size_t)M_*256*2);
    u16*   LH   = (u16*)  alloc((size_t)M_*256*2);
    u16*   CONC = (u16*)  alloc((size_t)M_*256*2);
    u16*   GOUT = (u16*)  alloc((size_t)M_*256*2);
    u16*   MOUT = (u16*)  alloc((size_t)M_*256*2);
    u16*   PRE1h= (u16*)  alloc((size_t)M_*256*2);
    u16*   PRh  = (u16*)  alloc((size_t)M_*256*2);
    u16*   GSUM = (u16*)  alloc((size_t)M_*256*2);
    u16*   CS1  = (u16*)  alloc((size_t)M_*256*2);
    u16*   H1   = (u16*)  alloc((size_t)M_*512*2);
    u16*   SCALEDh=(u16*) alloc((size_t)M_*256*2);
    u16*   STATESh=(u16*) alloc((size_t)M_*256*2);
    u16*   FFNIN= (u16*)  alloc((size_t)M_*256*2);
    u16*   H2   = (u16*)  alloc((size_t)M_*1024*2);
    u16*   PRE2h= (u16*)  alloc((size_t)M_*256*2);
    float* CAR0 = (float*)alloc((size_t)B_*NC_*D_*4);
    float* CAR1 = (float*)alloc((size_t)B_*NC_*D_*4);

    float* out_pr = (float*)d_out;
    float* out_fs = out_pr + (size_t)M_*256;
    float* out_tj = out_fs + B_*256;

    const dim3 blk256(256), blk512(512);
    const dim3 scan_grid(NC_, B_);
    const int NRg = M_/128;   // 64 row tiles

    // 0. convert weights + X to bf16, bias concat, fused depthwise conv -> LH
    cvt_conv_k<<<dim3(CVT_BLKS + CONV_BLKS), blk256, 0, stream>>>(
        qkv_w, gkv_w, qkv_b, gkv_b, mo_w, fg_w, go_w, comb_w,
        ffn1_w, ffn2_w, tr1_w, tr2_w, p2s_w, s2p_w, X, conv_w, conv_b,
        Wh, Xh, bq, LH);
    // 1. fused qkv+gkv projection -> QKVG (bf16)
    gemm_k<<<dim3(NRg*20), blk512, 0, stream>>>(
        Xh, Wh+OFF_QKV, 256, 256,  nullptr,nullptr,0,0,  nullptr,nullptr,0,0,
        bq, nullptr, 0, QKVG, 1280, 1, OP_NONE, 20);
    // 2. banded attention -> MED bf16
    attn_k<<<dim3(T_/64, H_, B_), blk256, 0, stream>>>(QKVG, MED);
    // 3. mo projection -> MED2 bf16
    gemm_k<<<dim3(NRg*4), blk512, 0, stream>>>(
        MED, Wh+OFF_MO, 256, 256,  nullptr,nullptr,0,0,  nullptr,nullptr,0,0,
        mo_b, nullptr, 0, MED2, 256, 1, OP_NONE, 4);
    // 4. concepts scan -> CONC bf16
    scan1_p1<<<scan_grid, blk256, 0, stream>>>(QKVG, CAR0, CAR1);
    scan1_p3<<<scan_grid, blk256, 0, stream>>>(QKVG, CAR0, CAR1, CONC);
    // 5. global_out -> GOUT bf16
    gemm_k<<<dim3(NRg*4), blk512, 0, stream>>>(
        CONC, Wh+OFF_GO, 256, 256,  nullptr,nullptr,0,0,  nullptr,nullptr,0,0,
        go_b, nullptr, 0, GOUT, 256, 1, OP_NONE, 4);
    // 6. medium_out = MED2 * sigmoid([X,MED2]@fg^T + b) -> MOUT bf16
    gemm_k<<<dim3(NRg*4), blk512, 0, stream>>>(
        Xh, Wh+OFF_FG, 512, 256,  MED2, Wh+OFF_FG+256, 512, 256,  nullptr,nullptr,0,0,
        fg_b, MED2, 1, MOUT, 256, 1, OP_SIGMUL, 4);
    // 7. pre_ln1 = X + [LH,MOUT,GOUT]@comb^T + b -> PRE1h bf16
    gemm_k<<<dim3(NRg*4), blk512, 0, stream>>>(
        LH, Wh+OFF_COMB, 768, 256,  MOUT, Wh+OFF_COMB+256, 768, 256,  GOUT, Wh+OFF_COMB+512, 768, 256,
        comb_b, X, 0, PRE1h, 256, 1, OP_ADDAUX, 4);
    // 8. pr = LN1 -> PRh bf16, fused gsum EMA p1 -> CAR0
    ln1ema_k<<<scan_grid, blk256, 0, stream>>>(PRE1h, ln1_g, ln1_b, PRh, CAR0);
    // 9. gsum EMA replay -> GSUM bf16 + traj
    ema_p3h<<<scan_grid, blk256, 0, stream>>>(PRh, CAR0, GSUM, 0.1f, out_tj);
    // 10. cs1 = pr + 0.3*(pr@p2s^T + b) -> CS1 bf16
    gemm_k<<<dim3(NRg*4), blk512, 0, stream>>>(
        PRh, Wh+OFF_P2S, 256, 256,  nullptr,nullptr,0,0,  nullptr,nullptr,0,0,
        p2s_b, PRh, 1, CS1, 256, 1, OP_AXPBY, 4);
    // 11. H1 = gelu(cs1@tr1a + gsum@tr1b + b) bf16
    gemm_k<<<dim3(NRg*8), blk512, 0, stream>>>(
        CS1, Wh+OFF_TR1, 512, 256,  GSUM, Wh+OFF_TR1+256, 512, 256,  nullptr,nullptr,0,0,
        tr1_b, nullptr, 0, H1, 512, 1, OP_GELU, 8);
    // 12. scaled = 0.5*tanh(H1@tr2^T + b) -> SCALEDh bf16
    gemm_k<<<dim3(NRg*4), blk512, 0, stream>>>(
        H1, Wh+OFF_TR2, 512, 512,  nullptr,nullptr,0,0,  nullptr,nullptr,0,0,
        tr2_b, nullptr, 0, SCALEDh, 256, 1, OP_TANHHALF, 4);
    // 13. state EMA p1 -> CAR0
    ema_p1h<<<scan_grid, blk256, 0, stream>>>(SCALEDh, CAR0, 1.0f);
    // 14. fused state EMA replay + LN3 + LN4 -> STATESh bf16, out_fs
    ema_ln3_k<<<scan_grid, blk256, 0, stream>>>(
        SCALEDh, CAR0, SEQ, ln3_g, ln3_b, STATESh, ln4_g, ln4_b, out_fs);
    // 15. ffn_in = pr + 0.3*(states@s2p^T + b) -> FFNIN bf16
    gemm_k<<<dim3(NRg*4), blk512, 0, stream>>>(
        STATESh, Wh+OFF_S2P, 256, 256,  nullptr,nullptr,0,0,  nullptr,nullptr,0,0,
        s2p_b, PRh, 1, FFNIN, 256, 1, OP_AXPBY, 4);
    // 16. H2 = gelu(ffn_in@ffn1^T + b) bf16
    gemm_k<<<dim3(NRg*16), blk512, 0, stream>>>(
        FFNIN, Wh+OFF_FFN1, 256, 256,  nullptr,nullptr,0,0,  nullptr,nullptr,0,0,
        ffn1_b, nullptr, 0, H2, 1024, 1, OP_GELU, 16);
    // 17. pre_ln2 = pr + H2@ffn2^T + b -> PRE2h bf16
    gemm_k<<<dim3(NRg*4), blk512, 0, stream>>>(
        H2, Wh+OFF_FFN2, 1024, 1024,  nullptr,nullptr,0,0,  nullptr,nullptr,0,0,
        ffn2_b, PRh, 1, PRE2h, 256, 1, OP_ADDAUX, 4);
    // 18. pr_out = LN2 -> d_out
    ln2h_k<<<dim3(M_/4), blk256, 0, stream>>>(PRE2h, ln2_g, ln2_b, out_pr);
}

// Round 13
// 238.627 us; speedup vs baseline: 1.5267x; 1.0618x over previous
//
#include <hip/hip_runtime.h>
#include <hip/hip_bf16.h>
#include <math.h>

#define D_  256
#define T_  2048
#define B_  4
#define M_  (B_*T_)
#define H_  4
#define HD_ 64

#define NC_ 64          // scan chunks
#define LCH (T_/NC_)    // 32 steps per chunk

enum { OP_NONE=0, OP_SIGMUL=1, OP_ADDAUX=2, OP_AXPBY=3, OP_GELU=4, OP_TANHHALF=5 };

typedef unsigned short u16;
typedef short short8 __attribute__((ext_vector_type(8)));
typedef float f32x4  __attribute__((ext_vector_type(4)));

__device__ __forceinline__ float gelu_f(float x){ return 0.5f*x*(1.0f+erff(x*0.70710678118654752f)); }
__device__ __forceinline__ float sigmoid_f(float x){ return 1.0f/(1.0f+expf(-x)); }

__device__ __forceinline__ unsigned pk2(float a, float b){
    __hip_bfloat162 h = __float22bfloat162_rn(make_float2(a,b));
    union { __hip_bfloat162 h; unsigned u; } c; c.h = h; return c.u;
}
__device__ __forceinline__ float bfu(u16 u){ return __uint_as_float(((unsigned)u)<<16); }
__device__ __forceinline__ u16 bf1(float x){ return (u16)(pk2(x,x)&0xffffu); }

// weight-pack element offsets inside Wh (u16 elements)
#define OFF_QKV   0u        // fused qkv(768)+gkv(512) rows -> [1280,256]
#define OFF_MO    327680u
#define OFF_FG    393216u
#define OFF_GO    524288u
#define OFF_COMB  589824u
#define OFF_FFN1  786432u
#define OFF_FFN2  1048576u
#define OFF_TR1   1310720u
#define OFF_TR2   1572864u
#define OFF_P2S   1703936u
#define OFF_S2P   1769472u
#define NWELEM    1835008u
#define NXELEM    2097152u
#define CVT_BLKS  3842u
#define CONV_BLKS 2048u

// ---------------------------------------------------------------------------
// fp32 -> bf16 conversion of all weights + X, qkv/gkv bias concat, AND the
// depthwise causal conv (K=8) fused as a second block range (reads fp32 X).
// ---------------------------------------------------------------------------
__global__ __launch_bounds__(256) void cvt_conv_k(
    const float* __restrict__ qkv_w, const float* __restrict__ gkv_w,
    const float* __restrict__ qkv_b, const float* __restrict__ gkv_b,
    const float* __restrict__ mo_w,  const float* __restrict__ fg_w,
    const float* __restrict__ go_w,  const float* __restrict__ comb_w,
    const float* __restrict__ ffn1_w,const float* __restrict__ ffn2_w,
    const float* __restrict__ tr1_w, const float* __restrict__ tr2_w,
    const float* __restrict__ p2s_w, const float* __restrict__ s2p_w,
    const float* __restrict__ X,
    const float* __restrict__ conv_w, const float* __restrict__ conv_b,
    u16* __restrict__ Wh, u16* __restrict__ Xh, float* __restrict__ bq,
    u16* __restrict__ LH)
{
    if (blockIdx.x >= CVT_BLKS){
        int idx = (blockIdx.x - CVT_BLKS)*256 + threadIdx.x;   // over M*D/4
        int d4 = (idx & 63) * 4;
        int bt = idx >> 6;
        int t = bt & (T_-1);
        float a0 = conv_b[d4], a1 = conv_b[d4+1], a2 = conv_b[d4+2], a3 = conv_b[d4+3];
        const float* xp = X + (size_t)bt*D_ + d4;
        #pragma unroll
        for (int j=0;j<8;++j){
            int tt = t - 7 + j;
            if (tt >= 0){
                float4 v = *(const float4*)(xp + (size_t)(j-7)*D_);
                a0 += v.x * conv_w[(d4+0)*8 + j];
                a1 += v.y * conv_w[(d4+1)*8 + j];
                a2 += v.z * conv_w[(d4+2)*8 + j];
                a3 += v.w * conv_w[(d4+3)*8 + j];
            }
        }
        *(uint2*)(LH + (size_t)bt*D_ + d4) = (uint2){ pk2(a0,a1), pk2(a2,a3) };
        return;
    }
    size_t i = ((size_t)blockIdx.x*256 + threadIdx.x)*4;
    if (i < NWELEM){
        const float* s; size_t base;
        if      (i < OFF_MO)  { s=(i<196608)?qkv_w:gkv_w; base=(i<196608)?0:196608; }
        else if (i < OFF_FG)  { s=mo_w;   base=OFF_MO; }
        else if (i < OFF_GO)  { s=fg_w;   base=OFF_FG; }
        else if (i < OFF_COMB){ s=go_w;   base=OFF_GO; }
        else if (i < OFF_FFN1){ s=comb_w; base=OFF_COMB; }
        else if (i < OFF_FFN2){ s=ffn1_w; base=OFF_FFN1; }
        else if (i < OFF_TR1) { s=ffn2_w; base=OFF_FFN2; }
        else if (i < OFF_TR2) { s=tr1_w;  base=OFF_TR1; }
        else if (i < OFF_P2S) { s=tr2_w;  base=OFF_TR2; }
        else if (i < OFF_S2P) { s=p2s_w;  base=OFF_P2S; }
        else                  { s=s2p_w;  base=OFF_S2P; }
        float4 v = *(const float4*)(s + (i-base));
        *(uint2*)(Wh + i) = (uint2){ pk2(v.x,v.y), pk2(v.z,v.w) };
    } else if (i < NWELEM + NXELEM){
        size_t j = i - NWELEM;
        float4 v = *(const float4*)(X + j);
        *(uint2*)(Xh + j) = (uint2){ pk2(v.x,v.y), pk2(v.z,v.w) };
    } else if (i < NWELEM + NXELEM + 1280){
        size_t j = i - (NWELEM + NXELEM);
        #pragma unroll
        for (int k=0;k<4;++k){
            size_t e = j + k;
            bq[e] = (e < 768) ? qkv_b[e] : gkv_b[e-768];
        }
    }
}

// ---------------------------------------------------------------------------
// bf16 MFMA GEMM (r9 structure) + optional independent "tail" block range:
//   tailOp 1: scan1_p3 (concepts replay)      tailOp 2: ema_p3h (gsum replay)
// Tail blocks use only threads < 256 and touch none of the GEMM's outputs.
// ---------------------------------------------------------------------------
__global__ __launch_bounds__(512) void gemm_k(
    const u16* __restrict__ A0, const u16* __restrict__ W0, int ldw0, int K0,
    const u16* __restrict__ A1, const u16* __restrict__ W1, int ldw1, int K1,
    const u16* __restrict__ A2, const u16* __restrict__ W2, int ldw2, int K2,
    const float* __restrict__ bias, const void* __restrict__ aux, int aux_bf16,
    void* __restrict__ C, int ldc, int c_bf16, int op, int ncol,
    int gemmBlocks, int tailOp,
    const u16* __restrict__ tIn, const float* __restrict__ tC0,
    const float* __restrict__ tC1, u16* __restrict__ tOut, float* __restrict__ tTraj)
{
    if ((int)blockIdx.x >= gemmBlocks){
        if (threadIdx.x < 256){
            const int j = blockIdx.x - gemmBlocks;
            const int c = j & (NC_-1), b = j >> 6;
            const int d = threadIdx.x;
            if (tailOp == 1){
                float sgk = 0.f, sgkv = 0.f;
                for (int cc=0; cc<c; ++cc){
                    sgk  += tC0[((size_t)b*NC_ + cc)*D_ + d];
                    sgkv += tC1[((size_t)b*NC_ + cc)*D_ + d];
                }
                const u16* base = tIn + ((size_t)(b*T_ + c*LCH))*1280;
                u16* out = tOut + ((size_t)(b*T_ + c*LCH))*D_ + d;
                for (int t=0;t<LCH;++t){
                    float gk = bfu(base[(size_t)t*1280 + 768 + d]);
                    gk = gk > 0.f ? gk + 1.f : expf(gk);
                    float gv = bfu(base[(size_t)t*1280 + 1024 + d]);
                    sgk += gk; sgkv += gk*gv;
                    out[(size_t)t*D_] = bf1(sgkv / (sgk + 1e-5f));
                }
            } else {
                const float dL = powf(0.9f, (float)LCH);
                float g = 0.f;
                for (int cc=0; cc<c; ++cc) g = tC0[((size_t)b*NC_ + cc)*D_ + d] + dL*g;
                const u16* xp = tIn + ((size_t)(b*T_ + c*LCH))*D_ + d;
                u16* op2 = tOut + ((size_t)(b*T_ + c*LCH))*D_ + d;
                for (int t=0;t<LCH;++t){
                    g = 0.9f*g + 0.1f*bfu(xp[(size_t)t*D_]);
                    op2[(size_t)t*D_] = bf1(g);
                }
                if (c == NC_-1) tTraj[b*D_ + d] = g;
            }
        }
        return;
    }

    __shared__ u16 As[128*64];
    __shared__ u16 Ws[64*64];

    const int q8   = gemmBlocks >> 3;
    const int lid  = (blockIdx.x & 7)*q8 + (blockIdx.x >> 3);
    const int brow = lid / ncol;
    const int bcol = lid - brow*ncol;
    const int row0 = brow*128, col0 = bcol*64;

    const int tid  = threadIdx.x;
    const int lane = tid & 63, wid = tid >> 6;
    const int wm = (wid >> 1)*32, wn = (wid & 1)*32;
    const int l15 = lane & 15, l4 = lane >> 4;
    const int rowA = tid >> 2;            // 0..127
    const int scA  = (tid & 3) * 8;
    const int rowW = tid >> 3;            // 0..63
    const int scW  = (tid & 7) * 8;

    f32x4 acc[2][2];
    #pragma unroll
    for (int i=0;i<2;++i)
        #pragma unroll
        for (int j=0;j<2;++j) acc[i][j] = (f32x4){0.f,0.f,0.f,0.f};

    uint4 ra0, ra1, rw0;

    auto loadtile = [&](const u16* A, const u16* W, int ldw, int K, int kb){
        const u16* ga = A + (size_t)(row0+rowA)*K + kb + scA;
        ra0 = *(const uint4*)ga;
        ra1 = *(const uint4*)(ga + 32);
        rw0 = *(const uint4*)(W + (size_t)(col0+rowW)*ldw + kb + scW);
    };
    auto storetile = [&](){
        const int sw = (rowA&7)<<3;
        *(uint4*)&As[(rowA*64 + scA) ^ sw]      = ra0;
        *(uint4*)&As[(rowA*64 + scA + 32) ^ sw] = ra1;
        *(uint4*)&Ws[(rowW*64 + scW) ^ ((rowW&7)<<3)] = rw0;
    };
    auto mfma_tile = [&](){
        #pragma unroll
        for (int ks=0;ks<2;++ks){
            const int koff = ks*32 + l4*8;
            short8 af[2], bf[2];
            #pragma unroll
            for (int f=0;f<2;++f){
                const int ar = wm + f*16 + l15;
                af[f] = *(const short8*)&As[(ar*64 + koff) ^ ((ar&7)<<3)];
                const int brn = wn + f*16 + l15;
                bf[f] = *(const short8*)&Ws[(brn*64 + koff) ^ ((brn&7)<<3)];
            }
            #pragma unroll
            for (int fm=0;fm<2;++fm)
                #pragma unroll
                for (int fn=0;fn<2;++fn)
                    acc[fm][fn] = __builtin_amdgcn_mfma_f32_16x16x32_bf16(
                        af[fm], bf[fn], acc[fm][fn], 0, 0, 0);
        }
    };

    const u16* Ac = A0; const u16* Wc = W0; int ldwc = ldw0, Kc = K0, kb = 0;
    loadtile(Ac, Wc, ldwc, Kc, 0);
    while (true){
        __syncthreads();            // prev MFMA done; LDS free
        storetile();
        __syncthreads();            // staged tile visible
        int nkb = kb + 64;
        const u16* nA = Ac; const u16* nW = Wc; int nld = ldwc, nK = Kc;
        bool have_next = true;
        if (nkb >= Kc){
            if (Ac == A0 && A1){ nA = A1; nW = W1; nld = ldw1; nK = K1; nkb = 0; }
            else if (Ac == A1 && A2){ nA = A2; nW = W2; nld = ldw2; nK = K2; nkb = 0; }
            else have_next = false;
        }
        if (have_next) loadtile(nA, nW, nld, nK, nkb);   // in flight across MFMA
        mfma_tile();
        if (!have_next) break;
        Ac = nA; Wc = nW; ldwc = nld; Kc = nK; kb = nkb;
    }

    #pragma unroll
    for (int fn=0;fn<2;++fn){
        const int n = col0 + wn + fn*16 + l15;
        const float bv = bias[n];
        #pragma unroll
        for (int fm=0;fm<2;++fm){
            #pragma unroll
            for (int j=0;j<4;++j){
                const int m = row0 + wm + fm*16 + l4*4 + j;
                float v = acc[fm][fn][j] + bv;
                if (op==OP_GELU)          v = gelu_f(v);
                else if (op==OP_TANHHALF) v = 0.5f*tanhf(v);
                else if (op!=OP_NONE){
                    const size_t ai = (size_t)m*D_ + n;
                    const float a = aux_bf16 ? bfu(((const u16*)aux)[ai])
                                             : ((const float*)aux)[ai];
                    if (op==OP_SIGMUL)      v = a*sigmoid_f(v);
                    else if (op==OP_ADDAUX) v = v + a;
                    else                    v = a + 0.3f*v;
                }
                if (c_bf16) ((u16*)C)[(size_t)m*ldc + n] = bf1(v);
                else        ((float*)C)[(size_t)m*ldc + n] = v;
            }
        }
    }
}

// ---------------------------------------------------------------------------
// Merged: MFMA banded attention (blocks 0..511) + scan1_p1 (blocks 512..767).
// Both read only QKVG.
// ---------------------------------------------------------------------------
__global__ __launch_bounds__(256) void attn_scan_k(const u16* __restrict__ QKVG,
    u16* __restrict__ MED, float* __restrict__ CA, float* __restrict__ CC)
{
    const int tid = threadIdx.x;
    if (blockIdx.x >= 512){
        const int j = blockIdx.x - 512;
        const int c = j & (NC_-1), b = j >> 6;
        const int d = tid;
        const u16* base = QKVG + ((size_t)(b*T_ + c*LCH))*1280;
        float sgk=0.f, sgkv=0.f;
        for (int t=0;t<LCH;++t){
            float gk = bfu(base[(size_t)t*1280 + 768 + d]);
            gk = gk > 0.f ? gk + 1.f : expf(gk);
            float gv = bfu(base[(size_t)t*1280 + 1024 + d]);
            sgk += gk; sgkv += gk*gv;
        }
        CA[((size_t)b*NC_ + c)*D_ + d] = sgk;
        CC[((size_t)b*NC_ + c)*D_ + d] = sgkv;
        return;
    }

    __shared__ u16 Kl[128*64];
    __shared__ u16 Ql[64*64];
    __shared__ u16 Vl[64*128];
    const int b = blockIdx.x >> 7, h = (blockIdx.x >> 5) & 3;
    const int t0 = (blockIdx.x & 31) * 64;
    const int kb0 = t0 - 64;

    {
        const int r0 = tid >> 3, c8 = (tid & 7) * 8;
        #pragma unroll
        for (int rep=0;rep<4;++rep){
            const int r = r0 + rep*32;
            const int kg = kb0 + r;
            uint4 pk = {0,0,0,0}, pv = {0,0,0,0};
            if (kg >= 0){
                const u16* gp = QKVG + ((size_t)(b*T_ + kg))*1280 + h*HD_ + c8;
                pk = *(const uint4*)(gp + 256);
                pv = *(const uint4*)(gp + 512);
            }
            *(uint4*)&Kl[(r*64 + c8) ^ ((r&7)<<3)] = pk;
            const u16* pvu = (const u16*)&pv;
            #pragma unroll
            for (int j=0;j<8;++j){
                const int d = c8 + j;
                Vl[(d*128 + r) ^ ((d&15)<<3)] = pvu[j];
            }
        }
        #pragma unroll
        for (int rep=0;rep<2;++rep){
            const int r = r0 + rep*32;
            uint4 pq = *(const uint4*)(QKVG + ((size_t)(b*T_ + t0 + r))*1280 + h*HD_ + c8);
            *(uint4*)&Ql[(r*64 + c8) ^ ((r&7)<<3)] = pq;
        }
    }
    __syncthreads();

    const int lane = tid & 63, w = tid >> 6;
    const int l15 = lane & 15, l4 = lane >> 4;

    short8 bq[2];
    {
        const int qr = w*16 + l15;
        bq[0] = *(const short8*)&Ql[(qr*64 +      l4*8) ^ ((qr&7)<<3)];
        bq[1] = *(const short8*)&Ql[(qr*64 + 32 + l4*8) ^ ((qr&7)<<3)];
    }

    f32x4 s[8];
    #pragma unroll
    for (int kf=0;kf<8;++kf){
        const int kr = kf*16 + l15;
        short8 a0 = *(const short8*)&Kl[(kr*64 +      l4*8) ^ ((kr&7)<<3)];
        short8 a1 = *(const short8*)&Kl[(kr*64 + 32 + l4*8) ^ ((kr&7)<<3)];
        f32x4 acc = (f32x4){0.f,0.f,0.f,0.f};
        acc = __builtin_amdgcn_mfma_f32_16x16x32_bf16(a0, bq[0], acc, 0,0,0);
        acc = __builtin_amdgcn_mfma_f32_16x16x32_bf16(a1, bq[1], acc, 0,0,0);
        s[kf] = acc;
    }

    const int qg = t0 + w*16 + l15;
    float m = -1e30f;
    #pragma unroll
    for (int kf=0;kf<8;++kf){
        #pragma unroll
        for (int j=0;j<4;++j){
            const int kg = kb0 + kf*16 + l4*4 + j;
            const int diff = qg - kg;
            const float v = (kg >= 0 && diff >= 0 && diff < 64) ? s[kf][j]*0.125f : -1e30f;
            s[kf][j] = v;
            m = fmaxf(m, v);
        }
    }
    m = fmaxf(m, __shfl_xor(m,16));
    m = fmaxf(m, __shfl_xor(m,32));
    float lsum = 0.f;
    unsigned lo[8], hi[8];
    #pragma unroll
    for (int kf=0;kf<8;++kf){
        const float p0 = expf(s[kf][0]-m), p1 = expf(s[kf][1]-m);
        const float p2 = expf(s[kf][2]-m), p3 = expf(s[kf][3]-m);
        lsum += (p0+p1)+(p2+p3);
        lo[kf] = pk2(p0,p1);
        hi[kf] = pk2(p2,p3);
    }
    lsum += __shfl_xor(lsum,16);
    lsum += __shfl_xor(lsum,32);
    const float inv = 1.f/lsum;

    f32x4 o[4];
    #pragma unroll
    for (int df=0;df<4;++df) o[df] = (f32x4){0.f,0.f,0.f,0.f};
    const int baseLane = l15 + ((l4&1)<<5);
    const bool hiHalf = (l4>>1) != 0;
    #pragma unroll
    for (int kb=0;kb<4;++kb){
        const int x0 = __shfl((int)lo[2*kb],   baseLane);
        const int x1 = __shfl((int)hi[2*kb],   baseLane);
        const int x2 = __shfl((int)lo[2*kb],   baseLane+16);
        const int x3 = __shfl((int)hi[2*kb],   baseLane+16);
        const int y0 = __shfl((int)lo[2*kb+1], baseLane);
        const int y1 = __shfl((int)hi[2*kb+1], baseLane);
        const int y2 = __shfl((int)lo[2*kb+1], baseLane+16);
        const int y3 = __shfl((int)hi[2*kb+1], baseLane+16);
        int4 afi;
        afi.x = hiHalf ? y0 : x0;
        afi.y = hiHalf ? y1 : x1;
        afi.z = hiHalf ? y2 : x2;
        afi.w = hiHalf ? y3 : x3;
        union { int4 i; short8 s; } cv; cv.i = afi;
        #pragma unroll
        for (int df=0;df<4;++df){
            const int vr = df*16 + l15;
            short8 bv = *(const short8*)&Vl[(vr*128 + kb*32 + l4*8) ^ ((vr&15)<<3)];
            o[df] = __builtin_amdgcn_mfma_f32_16x16x32_bf16(cv.s, bv, o[df], 0,0,0);
        }
    }

    #pragma unroll
    for (int j=0;j<4;++j){
        const float invj = __shfl(inv, l4*4 + j);
        const int mrow = b*T_ + t0 + w*16 + l4*4 + j;
        u16* op = MED + (size_t)mrow*D_ + h*HD_ + l15;
        #pragma unroll
        for (int df=0;df<4;++df)
            op[df*16] = bf1(o[df][j] * invj);
    }
}

// ---------------------------------------------------------------------------
// EMA p1 (bf16 input) — still standalone for the state scan.
// ---------------------------------------------------------------------------
__global__ __launch_bounds__(256) void ema_p1h(const u16* __restrict__ X,
    float* __restrict__ CARRY, float alpha)
{
    const int d = threadIdx.x, c = blockIdx.x, b = blockIdx.y;
    const u16* xp = X + ((size_t)(b*T_ + c*LCH))*D_ + d;
    float g = 0.f;
    for (int t=0;t<LCH;++t) g = 0.9f*g + alpha*bfu(xp[(size_t)t*D_]);
    CARRY[((size_t)b*NC_ + c)*D_ + d] = g;
}

// ---------------------------------------------------------------------------
// Fused LN1 + gsum-EMA chunk aggregate.
// ---------------------------------------------------------------------------
__global__ __launch_bounds__(256) void ln1ema_k(const u16* __restrict__ in,
    const float* __restrict__ g, const float* __restrict__ b,
    u16* __restrict__ out, float* __restrict__ CARRY)
{
    __shared__ float wacc[4][256];
    const int c = blockIdx.x, bb = blockIdx.y;
    const int w = threadIdx.x >> 6, lane = threadIdx.x & 63;
    const int db = lane*4;
    const int row0 = bb*T_ + c*LCH;
    float acc0=0.f, acc1=0.f, acc2=0.f, acc3=0.f;
    #pragma unroll
    for (int it=0; it<8; ++it){
        const int r = it*4 + w;
        uint2 u = *(const uint2*)(in + (size_t)(row0 + r)*D_ + db);
        float x0=bfu((u16)(u.x&0xffff)), x1=bfu((u16)(u.x>>16));
        float x2=bfu((u16)(u.y&0xffff)), x3=bfu((u16)(u.y>>16));
        float s  = x0+x1+x2+x3;
        float s2 = x0*x0+x1*x1+x2*x2+x3*x3;
        #pragma unroll
        for (int o=1;o<64;o<<=1){ s += __shfl_xor(s,o); s2 += __shfl_xor(s2,o); }
        float mean = s*(1.f/256.f);
        float var  = s2*(1.f/256.f) - mean*mean;
        float rs = rsqrtf(var + 1e-5f);
        float y0=(x0-mean)*rs*g[db+0]+b[db+0];
        float y1=(x1-mean)*rs*g[db+1]+b[db+1];
        float y2=(x2-mean)*rs*g[db+2]+b[db+2];
        float y3=(x3-mean)*rs*g[db+3]+b[db+3];
        *(uint2*)(out + (size_t)(row0+r)*D_ + db) = (uint2){ pk2(y0,y1), pk2(y2,y3) };
        const float wt = 0.1f*powf(0.9f, (float)(31-r));
        acc0 += wt*y0; acc1 += wt*y1; acc2 += wt*y2; acc3 += wt*y3;
    }
    wacc[w][db+0]=acc0; wacc[w][db+1]=acc1; wacc[w][db+2]=acc2; wacc[w][db+3]=acc3;
    __syncthreads();
    const int d = threadIdx.x;
    CARRY[((size_t)bb*NC_ + c)*D_ + d] =
        wacc[0][d] + wacc[1][d] + wacc[2][d] + wacc[3][d];
}

// ---------------------------------------------------------------------------
// Fused state-EMA replay + LN3 (+LN4 on the final row).
// ---------------------------------------------------------------------------
__global__ __launch_bounds__(256) void ema_ln3_k(const u16* __restrict__ X,
    const float* __restrict__ CARRY, const float* __restrict__ SEQ,
    const float* __restrict__ g3, const float* __restrict__ b3, u16* __restrict__ states,
    const float* __restrict__ g4, const float* __restrict__ b4, float* __restrict__ fsout)
{
    __shared__ float vals[LCH][256];
    __shared__ float mv[LCH][2];
    __shared__ float st4[256];
    __shared__ float red[8];
    const int d = threadIdx.x, c = blockIdx.x, bb = blockIdx.y;
    const float dL = powf(0.9f, (float)LCH);
    float a = 0.f;
    for (int cc=0; cc<c; ++cc) a = CARRY[((size_t)bb*NC_ + cc)*D_ + d] + dL*a;
    const float ss = SEQ[bb*D_ + d];
    float dp = powf(0.9f, (float)(c*LCH + 1));
    const u16* xp = X + ((size_t)(bb*T_ + c*LCH))*D_ + d;
    for (int t=0;t<LCH;++t){
        a = 0.9f*a + bfu(xp[(size_t)t*D_]);
        vals[t][d] = fmaf(ss, dp, a);
        dp *= 0.9f;
    }
    __syncthreads();
    {
        const int r = threadIdx.x >> 3, seg = threadIdx.x & 7;
        float s=0.f, s2=0.f;
        #pragma unroll
        for (int j=0;j<32;++j){ float v = vals[r][seg*32+j]; s += v; s2 += v*v; }
        s += __shfl_xor(s,1); s2 += __shfl_xor(s2,1);
        s += __shfl_xor(s,2); s2 += __shfl_xor(s2,2);
        s += __shfl_xor(s,4); s2 += __shfl_xor(s2,4);
        if (seg == 0){
            float mean = s*(1.f/256.f);
            float var  = s2*(1.f/256.f) - mean*mean;
            mv[r][0] = mean; mv[r][1] = rsqrtf(var + 1e-5f);
        }
    }
    __syncthreads();
    const float gd = g3[d], bd = b3[d];
    const bool isLast = (c == NC_-1);
    u16* sp = states + ((size_t)(bb*T_ + c*LCH))*D_ + d;
    for (int t=0;t<LCH;++t){
        float st = (vals[t][d] - mv[t][0])*mv[t][1]*gd + bd;
        sp[(size_t)t*D_] = bf1(st);
        if (isLast && t == LCH-1) st4[d] = st;
    }
    if (isLast){
        __syncthreads();
        float v = st4[d];
        float s = v, s2 = v*v;
        #pragma unroll
        for (int o=1;o<64;o<<=1){ s += __shfl_xor(s,o); s2 += __shfl_xor(s2,o); }
        if ((threadIdx.x & 63) == 0){ red[threadIdx.x>>6] = s; red[4+(threadIdx.x>>6)] = s2; }
        __syncthreads();
        float S  = red[0]+red[1]+red[2]+red[3];
        float S2 = red[4]+red[5]+red[6]+red[7];
        float m2 = S*(1.f/256.f);
        float r2 = rsqrtf(S2*(1.f/256.f) - m2*m2 + 1e-5f);
        fsout[bb*D_ + d] = (st4[d]-m2)*r2*g4[d] + b4[d];
    }
}

// ---------------------------------------------------------------------------
// LN2: bf16 in, fp32 out (final pr_out).
// ---------------------------------------------------------------------------
__global__ __launch_bounds__(256) void ln2h_k(const u16* __restrict__ in,
    const float* __restrict__ g, const float* __restrict__ b, float* __restrict__ out)
{
    int row  = blockIdx.x*4 + (threadIdx.x>>6);
    int lane = threadIdx.x & 63;
    uint2 u = *(const uint2*)(in + (size_t)row*D_ + lane*4);
    float x0=bfu((u16)(u.x&0xffff)), x1=bfu((u16)(u.x>>16));
    float x2=bfu((u16)(u.y&0xffff)), x3=bfu((u16)(u.y>>16));
    float s  = x0+x1+x2+x3;
    float s2 = x0*x0+x1*x1+x2*x2+x3*x3;
    #pragma unroll
    for (int o=1;o<64;o<<=1){ s += __shfl_xor(s,o); s2 += __shfl_xor(s2,o); }
    float mean = s * (1.f/256.f);
    float var  = s2 * (1.f/256.f) - mean*mean;
    float rs = rsqrtf(var + 1e-5f);
    int db = lane*4;
    float4 r;
    r.x=(x0-mean)*rs*g[db+0]+b[db+0];
    r.y=(x1-mean)*rs*g[db+1]+b[db+1];
    r.z=(x2-mean)*rs*g[db+2]+b[db+2];
    r.w=(x3-mean)*rs*g[db+3]+b[db+3];
    *(float4*)(out + (size_t)row*D_ + db) = r;
}

// ---------------------------------------------------------------------------
extern "C" void kernel_launch(void* const* d_in, const int* in_sizes, int n_in,
                              void* d_out, int out_size, void* d_ws, size_t ws_size,
                              hipStream_t stream)
{
    const float* X     = (const float*)d_in[0];
    const float* SEQ   = (const float*)d_in[1];
    const float* conv_w= (const float*)d_in[3];
    const float* conv_b= (const float*)d_in[4];
    const float* qkv_w = (const float*)d_in[5];
    const float* qkv_b = (const float*)d_in[6];
    const float* mo_w  = (const float*)d_in[7];
    const float* mo_b  = (const float*)d_in[8];
    const float* fg_w  = (const float*)d_in[9];
    const float* fg_b  = (const float*)d_in[10];
    const float* gkv_w = (const float*)d_in[11];
    const float* gkv_b = (const float*)d_in[12];
    const float* go_w  = (const float*)d_in[13];
    const float* go_b  = (const float*)d_in[14];
    const float* comb_w= (const float*)d_in[15];
    const float* comb_b= (const float*)d_in[16];
    const float* ffn1_w= (const float*)d_in[17];
    const float* ffn1_b= (const float*)d_in[18];
    const float* ffn2_w= (const float*)d_in[19];
    const float* ffn2_b= (const float*)d_in[20];
    const float* tr1_w = (const float*)d_in[21];
    const float* tr1_b = (const float*)d_in[22];
    const float* tr2_w = (const float*)d_in[23];
    const float* tr2_b = (const float*)d_in[24];
    const float* p2s_w = (const float*)d_in[25];
    const float* p2s_b = (const float*)d_in[26];
    const float* s2p_w = (const float*)d_in[27];
    const float* s2p_b = (const float*)d_in[28];
    const float* ln1_g = (const float*)d_in[29];
    const float* ln1_b = (const float*)d_in[30];
    const float* ln2_g = (const float*)d_in[31];
    const float* ln2_b = (const float*)d_in[32];
    const float* ln3_g = (const float*)d_in[33];
    const float* ln3_b = (const float*)d_in[34];
    const float* ln4_g = (const float*)d_in[35];
    const float* ln4_b = (const float*)d_in[36];

    // -------- workspace carve (256-byte aligned chunks) --------
    char* p = (char*)d_ws;
    auto alloc = [&](size_t bytes)->char*{ char* r = p; p += (bytes + 255) & ~(size_t)255; return r; };

    u16*   QKVG = (u16*)  alloc((size_t)M_*1280*2);
    u16*   Wh   = (u16*)  alloc((size_t)NWELEM*2);
    float* bq   = (float*)alloc(1280*4);
    u16*   Xh   = (u16*)  alloc((size_t)M_*256*2);
    u16*   MED  = (u16*)  alloc((size_t)M_*256*2);
    u16*   MED2 = (u16*)  alloc((size_t)M_*256*2);
    u16*   LH   = (u16*)  alloc((size_t)M_*256*2);
    u16*   CONC = (u16*)  alloc((size_t)M_*256*2);
    u16*   GOUT = (u16*)  alloc((size_t)M_*256*2);
    u16*   MOUT = (u16*)  alloc((size_t)M_*256*2);
    u16*   PRE1h= (u16*)  alloc((size_t)M_*256*2);
    u16*   PRh  = (u16*)  alloc((size_t)M_*256*2);
    u16*   GSUM = (u16*)  alloc((size_t)M_*256*2);
    u16*   CS1  = (u16*)  alloc((size_t)M_*256*2);
    u16*   H1   = (u16*)  alloc((size_t)M_*512*2);
    u16*   SCALEDh=(u16*) alloc((size_t)M_*256*2);
    u16*   STATESh=(u16*) alloc((size_t)M_*256*2);
    u16*   FFNIN= (u16*)  alloc((size_t)M_*256*2);
    u16*   H2   = (u16*)  alloc((size_t)M_*1024*2);
    u16*   PRE2h= (u16*)  alloc((size_t)M_*256*2);
    float* CAR0 = (float*)alloc((size_t)B_*NC_*D_*4);
    float* CAR1 = (float*)alloc((size_t)B_*NC_*D_*4);

    float* out_pr = (float*)d_out;
    float* out_fs = out_pr + (size_t)M_*256;
    float* out_tj = out_fs + B_*256;

    const dim3 blk256(256), blk512(512);
    const dim3 scan_grid(NC_, B_);
    const int NRg = M_/128;   // 64 row tiles

    // 0. convert weights + X to bf16, bias concat, fused depthwise conv -> LH
    cvt_conv_k<<<dim3(CVT_BLKS + CONV_BLKS), blk256, 0, stream>>>(
        qkv_w, gkv_w, qkv_b, gkv_b, mo_w, fg_w, go_w, comb_w,
        ffn1_w, ffn2_w, tr1_w, tr2_w, p2s_w, s2p_w, X, conv_w, conv_b,
        Wh, Xh, bq, LH);
    // 1. fused qkv+gkv projection -> QKVG (bf16)
    gemm_k<<<dim3(NRg*20), blk512, 0, stream>>>(
        Xh, Wh+OFF_QKV, 256, 256,  nullptr,nullptr,0,0,  nullptr,nullptr,0,0,
        bq, nullptr, 0, QKVG, 1280, 1, OP_NONE, 20,
        NRg*20, 0, nullptr, nullptr, nullptr, nullptr, nullptr);
    // 2. banded attention -> MED  ||  scan1_p1 -> CAR0/CAR1
    attn_scan_k<<<dim3(512 + 256), blk256, 0, stream>>>(QKVG, MED, CAR0, CAR1);
    // 3. mo projection -> MED2  ||  scan1_p3 -> CONC
    gemm_k<<<dim3(NRg*4 + 256), blk512, 0, stream>>>(
        MED, Wh+OFF_MO, 256, 256,  nullptr,nullptr,0,0,  nullptr,nullptr,0,0,
        mo_b, nullptr, 0, MED2, 256, 1, OP_NONE, 4,
        NRg*4, 1, QKVG, CAR0, CAR1, CONC, nullptr);
    // 4. global_out -> GOUT bf16
    gemm_k<<<dim3(NRg*4), blk512, 0, stream>>>(
        CONC, Wh+OFF_GO, 256, 256,  nullptr,nullptr,0,0,  nullptr,nullptr,0,0,
        go_b, nullptr, 0, GOUT, 256, 1, OP_NONE, 4,
        NRg*4, 0, nullptr, nullptr, nullptr, nullptr, nullptr);
    // 5. medium_out = MED2 * sigmoid([X,MED2]@fg^T + b) -> MOUT bf16
    gemm_k<<<dim3(NRg*4), blk512, 0, stream>>>(
        Xh, Wh+OFF_FG, 512, 256,  MED2, Wh+OFF_FG+256, 512, 256,  nullptr,nullptr,0,0,
        fg_b, MED2, 1, MOUT, 256, 1, OP_SIGMUL, 4,
        NRg*4, 0, nullptr, nullptr, nullptr, nullptr, nullptr);
    // 6. pre_ln1 = X + [LH,MOUT,GOUT]@comb^T + b -> PRE1h bf16
    gemm_k<<<dim3(NRg*4), blk512, 0, stream>>>(
        LH, Wh+OFF_COMB, 768, 256,  MOUT, Wh+OFF_COMB+256, 768, 256,  GOUT, Wh+OFF_COMB+512, 768, 256,
        comb_b, X, 0, PRE1h, 256, 1, OP_ADDAUX, 4,
        NRg*4, 0, nullptr, nullptr, nullptr, nullptr, nullptr);
    // 7. pr = LN1 -> PRh bf16, fused gsum EMA p1 -> CAR0
    ln1ema_k<<<scan_grid, blk256, 0, stream>>>(PRE1h, ln1_g, ln1_b, PRh, CAR0);
    // 8. cs1 = pr + 0.3*(pr@p2s^T + b) -> CS1  ||  gsum EMA replay -> GSUM + traj
    gemm_k<<<dim3(NRg*4 + 256), blk512, 0, stream>>>(
        PRh, Wh+OFF_P2S, 256, 256,  nullptr,nullptr,0,0,  nullptr,nullptr,0,0,
        p2s_b, PRh, 1, CS1, 256, 1, OP_AXPBY, 4,
        NRg*4, 2, PRh, CAR0, nullptr, GSUM, out_tj);
    // 9. H1 = gelu(cs1@tr1a + gsum@tr1b + b) bf16
    gemm_k<<<dim3(NRg*8), blk512, 0, stream>>>(
        CS1, Wh+OFF_TR1, 512, 256,  GSUM, Wh+OFF_TR1+256, 512, 256,  nullptr,nullptr,0,0,
        tr1_b, nullptr, 0, H1, 512, 1, OP_GELU, 8,
        NRg*8, 0, nullptr, nullptr, nullptr, nullptr, nullptr);
    // 10. scaled = 0.5*tanh(H1@tr2^T + b) -> SCALEDh bf16
    gemm_k<<<dim3(NRg*4), blk512, 0, stream>>>(
        H1, Wh+OFF_TR2, 512, 512,  nullptr,nullptr,0,0,  nullptr,nullptr,0,0,
        tr2_b, nullptr, 0, SCALEDh, 256, 1, OP_TANHHALF, 4,
        NRg*4, 0, nullptr, nullptr, nullptr, nullptr, nullptr);
    // 11. state EMA p1 -> CAR0
    ema_p1h<<<scan_grid, blk256, 0, stream>>>(SCALEDh, CAR0, 1.0f);
    // 12. fused state EMA replay + LN3 + LN4 -> STATESh bf16, out_fs
    ema_ln3_k<<<scan_grid, blk256, 0, stream>>>(
        SCALEDh, CAR0, SEQ, ln3_g, ln3_b, STATESh, ln4_g, ln4_b, out_fs);
    // 13. ffn_in = pr + 0.3*(states@s2p^T + b) -> FFNIN bf16
    gemm_k<<<dim3(NRg*4), blk512, 0, stream>>>(
        STATESh, Wh+OFF_S2P, 256, 256,  nullptr,nullptr,0,0,  nullptr,nullptr,0,0,
        s2p_b, PRh, 1, FFNIN, 256, 1, OP_AXPBY, 4,
        NRg*4, 0, nullptr, nullptr, nullptr, nullptr, nullptr);
    // 14. H2 = gelu(ffn_in@ffn1^T + b) bf16
    gemm_k<<<dim3(NRg*16), blk512, 0, stream>>>(
        FFNIN, Wh+OFF_FFN1, 256, 256,  nullptr,nullptr,0,0,  nullptr,nullptr,0,0,
        ffn1_b, nullptr, 0, H2, 1024, 1, OP_GELU, 16,
        NRg*16, 0, nullptr, nullptr, nullptr, nullptr, nullptr);
    // 15. pre_ln2 = pr + H2@ffn2^T + b -> PRE2h bf16
    gemm_k<<<dim3(NRg*4), blk512, 0, stream>>>(
        H2, Wh+OFF_FFN2, 1024, 1024,  nullptr,nullptr,0,0,  nullptr,nullptr,0,0,
        ffn2_b, PRh, 1, PRE2h, 256, 1, OP_ADDAUX, 4,
        NRg*4, 0, nullptr, nullptr, nullptr, nullptr, nullptr);
    // 16. pr_out = LN2 -> d_out
    ln2h_k<<<dim3(M_/4), blk256, 0, stream>>>(PRE2h, ln2_g, ln2_b, out_pr);
}

// Round 14
// 228.221 us; speedup vs baseline: 1.5964x; 1.0456x over previous
//
#include <hip/hip_runtime.h>
#include <hip/hip_bf16.h>
#include <math.h>

#define D_  256
#define T_  2048
#define B_  4
#define M_  (B_*T_)
#define H_  4
#define HD_ 64

#define NC_ 64          // scan chunks
#define LCH (T_/NC_)    // 32 steps per chunk

enum { OP_NONE=0, OP_SIGMUL=1, OP_ADDAUX=2, OP_AXPBY=3, OP_GELU=4, OP_TANHHALF=5 };

typedef unsigned short u16;
typedef short short8 __attribute__((ext_vector_type(8)));
typedef float f32x4  __attribute__((ext_vector_type(4)));

__device__ __forceinline__ float gelu_f(float x){ return 0.5f*x*(1.0f+erff(x*0.70710678118654752f)); }
__device__ __forceinline__ float sigmoid_f(float x){ return 1.0f/(1.0f+expf(-x)); }

__device__ __forceinline__ unsigned pk2(float a, float b){
    __hip_bfloat162 h = __float22bfloat162_rn(make_float2(a,b));
    union { __hip_bfloat162 h; unsigned u; } c; c.h = h; return c.u;
}
__device__ __forceinline__ float bfu(u16 u){ return __uint_as_float(((unsigned)u)<<16); }
__device__ __forceinline__ u16 bf1(float x){ return (u16)(pk2(x,x)&0xffffu); }

// weight-pack element offsets inside Wh (u16 elements)
#define OFF_QKV   0u
#define OFF_MO    327680u
#define OFF_FG    393216u
#define OFF_GO    524288u
#define OFF_COMB  589824u
#define OFF_FFN1  786432u
#define OFF_FFN2  1048576u
#define OFF_TR1   1310720u
#define OFF_TR2   1572864u
#define OFF_P2S   1703936u
#define OFF_S2P   1769472u
#define NWELEM    1835008u
#define NXELEM    2097152u
#define CVT_BLKS  3842u
#define CONV_BLKS 2048u

// ---------------------------------------------------------------------------
// fp32 -> bf16 conversion of all weights + X, qkv/gkv bias concat, AND the
// depthwise causal conv (K=8) fused as a second block range.
// ---------------------------------------------------------------------------
__global__ __launch_bounds__(256) void cvt_conv_k(
    const float* __restrict__ qkv_w, const float* __restrict__ gkv_w,
    const float* __restrict__ qkv_b, const float* __restrict__ gkv_b,
    const float* __restrict__ mo_w,  const float* __restrict__ fg_w,
    const float* __restrict__ go_w,  const float* __restrict__ comb_w,
    const float* __restrict__ ffn1_w,const float* __restrict__ ffn2_w,
    const float* __restrict__ tr1_w, const float* __restrict__ tr2_w,
    const float* __restrict__ p2s_w, const float* __restrict__ s2p_w,
    const float* __restrict__ X,
    const float* __restrict__ conv_w, const float* __restrict__ conv_b,
    u16* __restrict__ Wh, u16* __restrict__ Xh, float* __restrict__ bq,
    u16* __restrict__ LH)
{
    if (blockIdx.x >= CVT_BLKS){
        int idx = (blockIdx.x - CVT_BLKS)*256 + threadIdx.x;   // over M*D/4
        int d4 = (idx & 63) * 4;
        int bt = idx >> 6;
        int t = bt & (T_-1);
        float a0 = conv_b[d4], a1 = conv_b[d4+1], a2 = conv_b[d4+2], a3 = conv_b[d4+3];
        const float* xp = X + (size_t)bt*D_ + d4;
        #pragma unroll
        for (int j=0;j<8;++j){
            int tt = t - 7 + j;
            if (tt >= 0){
                float4 v = *(const float4*)(xp + (size_t)(j-7)*D_);
                a0 += v.x * conv_w[(d4+0)*8 + j];
                a1 += v.y * conv_w[(d4+1)*8 + j];
                a2 += v.z * conv_w[(d4+2)*8 + j];
                a3 += v.w * conv_w[(d4+3)*8 + j];
            }
        }
        *(uint2*)(LH + (size_t)bt*D_ + d4) = (uint2){ pk2(a0,a1), pk2(a2,a3) };
        return;
    }
    size_t i = ((size_t)blockIdx.x*256 + threadIdx.x)*4;
    if (i < NWELEM){
        const float* s; size_t base;
        if      (i < OFF_MO)  { s=(i<196608)?qkv_w:gkv_w; base=(i<196608)?0:196608; }
        else if (i < OFF_FG)  { s=mo_w;   base=OFF_MO; }
        else if (i < OFF_GO)  { s=fg_w;   base=OFF_FG; }
        else if (i < OFF_COMB){ s=go_w;   base=OFF_GO; }
        else if (i < OFF_FFN1){ s=comb_w; base=OFF_COMB; }
        else if (i < OFF_FFN2){ s=ffn1_w; base=OFF_FFN1; }
        else if (i < OFF_TR1) { s=ffn2_w; base=OFF_FFN2; }
        else if (i < OFF_TR2) { s=tr1_w;  base=OFF_TR1; }
        else if (i < OFF_P2S) { s=tr2_w;  base=OFF_TR2; }
        else if (i < OFF_S2P) { s=p2s_w;  base=OFF_P2S; }
        else                  { s=s2p_w;  base=OFF_S2P; }
        float4 v = *(const float4*)(s + (i-base));
        *(uint2*)(Wh + i) = (uint2){ pk2(v.x,v.y), pk2(v.z,v.w) };
    } else if (i < NWELEM + NXELEM){
        size_t j = i - NWELEM;
        float4 v = *(const float4*)(X + j);
        *(uint2*)(Xh + j) = (uint2){ pk2(v.x,v.y), pk2(v.z,v.w) };
    } else if (i < NWELEM + NXELEM + 1280){
        size_t j = i - (NWELEM + NXELEM);
        #pragma unroll
        for (int k=0;k<4;++k){
            size_t e = j + k;
            bq[e] = (e < 768) ? qkv_b[e] : gkv_b[e-768];
        }
    }
}

// ---------------------------------------------------------------------------
// Shared GEMM body (r9 structure): tile 128x64, BK=64, 8 waves (4Mx2N).
// Optional emaCar: fused state-EMA p1 chunk aggregates from the epilogue
// (each wave covers exactly one 32-row scan chunk).
// ---------------------------------------------------------------------------
__device__ __forceinline__ void gemm_body(
    u16* As, u16* Ws, int bid,
    const u16* __restrict__ A0, const u16* __restrict__ W0, int ldw0, int K0,
    const u16* __restrict__ A1, const u16* __restrict__ W1, int ldw1, int K1,
    const u16* __restrict__ A2, const u16* __restrict__ W2, int ldw2, int K2,
    const float* __restrict__ bias, const void* __restrict__ aux, int aux_bf16,
    void* __restrict__ C, int ldc, int c_bf16, int op, int ncol, int gemmBlocks,
    float* __restrict__ emaCar)
{
    const int q8   = gemmBlocks >> 3;
    const int lid  = (bid & 7)*q8 + (bid >> 3);
    const int brow = lid / ncol;
    const int bcol = lid - brow*ncol;
    const int row0 = brow*128, col0 = bcol*64;

    const int tid  = threadIdx.x;
    const int lane = tid & 63, wid = tid >> 6;
    const int wm = (wid >> 1)*32, wn = (wid & 1)*32;
    const int l15 = lane & 15, l4 = lane >> 4;
    const int rowA = tid >> 2;
    const int scA  = (tid & 3) * 8;
    const int rowW = tid >> 3;
    const int scW  = (tid & 7) * 8;

    f32x4 acc[2][2];
    #pragma unroll
    for (int i=0;i<2;++i)
        #pragma unroll
        for (int j=0;j<2;++j) acc[i][j] = (f32x4){0.f,0.f,0.f,0.f};

    uint4 ra0, ra1, rw0;

    auto loadtile = [&](const u16* A, const u16* W, int ldw, int K, int kb){
        const u16* ga = A + (size_t)(row0+rowA)*K + kb + scA;
        ra0 = *(const uint4*)ga;
        ra1 = *(const uint4*)(ga + 32);
        rw0 = *(const uint4*)(W + (size_t)(col0+rowW)*ldw + kb + scW);
    };
    auto storetile = [&](){
        const int sw = (rowA&7)<<3;
        *(uint4*)&As[(rowA*64 + scA) ^ sw]      = ra0;
        *(uint4*)&As[(rowA*64 + scA + 32) ^ sw] = ra1;
        *(uint4*)&Ws[(rowW*64 + scW) ^ ((rowW&7)<<3)] = rw0;
    };
    auto mfma_tile = [&](){
        #pragma unroll
        for (int ks=0;ks<2;++ks){
            const int koff = ks*32 + l4*8;
            short8 af[2], bf[2];
            #pragma unroll
            for (int f=0;f<2;++f){
                const int ar = wm + f*16 + l15;
                af[f] = *(const short8*)&As[(ar*64 + koff) ^ ((ar&7)<<3)];
                const int brn = wn + f*16 + l15;
                bf[f] = *(const short8*)&Ws[(brn*64 + koff) ^ ((brn&7)<<3)];
            }
            #pragma unroll
            for (int fm=0;fm<2;++fm)
                #pragma unroll
                for (int fn=0;fn<2;++fn)
                    acc[fm][fn] = __builtin_amdgcn_mfma_f32_16x16x32_bf16(
                        af[fm], bf[fn], acc[fm][fn], 0, 0, 0);
        }
    };

    const u16* Ac = A0; const u16* Wc = W0; int ldwc = ldw0, Kc = K0, kb = 0;
    loadtile(Ac, Wc, ldwc, Kc, 0);
    while (true){
        __syncthreads();
        storetile();
        __syncthreads();
        int nkb = kb + 64;
        const u16* nA = Ac; const u16* nW = Wc; int nld = ldwc, nK = Kc;
        bool have_next = true;
        if (nkb >= Kc){
            if (Ac == A0 && A1){ nA = A1; nW = W1; nld = ldw1; nK = K1; nkb = 0; }
            else if (Ac == A1 && A2){ nA = A2; nW = W2; nld = ldw2; nK = K2; nkb = 0; }
            else have_next = false;
        }
        if (have_next) loadtile(nA, nW, nld, nK, nkb);
        mfma_tile();
        if (!have_next) break;
        Ac = nA; Wc = nW; ldwc = nld; Kc = nK; kb = nkb;
    }

    #pragma unroll
    for (int fn=0;fn<2;++fn){
        const int n = col0 + wn + fn*16 + l15;
        const float bv = bias[n];
        float eacc = 0.f;
        #pragma unroll
        for (int fm=0;fm<2;++fm){
            #pragma unroll
            for (int j=0;j<4;++j){
                const int m = row0 + wm + fm*16 + l4*4 + j;
                float v = acc[fm][fn][j] + bv;
                if (op==OP_GELU)          v = gelu_f(v);
                else if (op==OP_TANHHALF) v = 0.5f*tanhf(v);
                else if (op!=OP_NONE){
                    const size_t ai = (size_t)m*D_ + n;
                    const float a = aux_bf16 ? bfu(((const u16*)aux)[ai])
                                             : ((const float*)aux)[ai];
                    if (op==OP_SIGMUL)      v = a*sigmoid_f(v);
                    else if (op==OP_ADDAUX) v = v + a;
                    else                    v = a + 0.3f*v;
                }
                if (c_bf16){
                    const u16 hv = bf1(v);
                    ((u16*)C)[(size_t)m*ldc + n] = hv;
                    if (emaCar){
                        const int rloc = fm*16 + l4*4 + j;        // row within chunk
                        eacc += powf(0.9f, (float)(31 - rloc)) * bfu(hv);
                    }
                } else {
                    ((float*)C)[(size_t)m*ldc + n] = v;
                }
            }
        }
        if (emaCar){
            eacc += __shfl_xor(eacc, 16);
            eacc += __shfl_xor(eacc, 32);
            if (l4 == 0){
                const int mw = row0 + wm;                  // chunk-aligned
                const int chunk = (mw >> 5) & (NC_-1);
                const int bbat  = mw >> 11;
                emaCar[((size_t)bbat*NC_ + chunk)*D_ + n] = eacc;
            }
        }
    }
}

// standard GEMM + optional independent tail (scan replays)
__global__ __launch_bounds__(512) void gemm_k(
    const u16* __restrict__ A0, const u16* __restrict__ W0, int ldw0, int K0,
    const u16* __restrict__ A1, const u16* __restrict__ W1, int ldw1, int K1,
    const u16* __restrict__ A2, const u16* __restrict__ W2, int ldw2, int K2,
    const float* __restrict__ bias, const void* __restrict__ aux, int aux_bf16,
    void* __restrict__ C, int ldc, int c_bf16, int op, int ncol,
    int gemmBlocks, int tailOp,
    const u16* __restrict__ tIn, const float* __restrict__ tC0,
    const float* __restrict__ tC1, u16* __restrict__ tOut, float* __restrict__ tTraj,
    float* __restrict__ emaCar)
{
    if ((int)blockIdx.x >= gemmBlocks){
        if (threadIdx.x < 256){
            const int j = blockIdx.x - gemmBlocks;
            const int c = j & (NC_-1), b = j >> 6;
            const int d = threadIdx.x;
            if (tailOp == 1){
                float sgk = 0.f, sgkv = 0.f;
                for (int cc=0; cc<c; ++cc){
                    sgk  += tC0[((size_t)b*NC_ + cc)*D_ + d];
                    sgkv += tC1[((size_t)b*NC_ + cc)*D_ + d];
                }
                const u16* base = tIn + ((size_t)(b*T_ + c*LCH))*1280;
                u16* out = tOut + ((size_t)(b*T_ + c*LCH))*D_ + d;
                for (int t=0;t<LCH;++t){
                    float gk = bfu(base[(size_t)t*1280 + 768 + d]);
                    gk = gk > 0.f ? gk + 1.f : expf(gk);
                    float gv = bfu(base[(size_t)t*1280 + 1024 + d]);
                    sgk += gk; sgkv += gk*gv;
                    out[(size_t)t*D_] = bf1(sgkv / (sgk + 1e-5f));
                }
            } else {
                const float dL = powf(0.9f, (float)LCH);
                float g = 0.f;
                for (int cc=0; cc<c; ++cc) g = tC0[((size_t)b*NC_ + cc)*D_ + d] + dL*g;
                const u16* xp = tIn + ((size_t)(b*T_ + c*LCH))*D_ + d;
                u16* op2 = tOut + ((size_t)(b*T_ + c*LCH))*D_ + d;
                for (int t=0;t<LCH;++t){
                    g = 0.9f*g + 0.1f*bfu(xp[(size_t)t*D_]);
                    op2[(size_t)t*D_] = bf1(g);
                }
                if (c == NC_-1) tTraj[b*D_ + d] = g;
            }
        }
        return;
    }
    __shared__ u16 As[128*64];
    __shared__ u16 Ws[64*64];
    gemm_body(As, Ws, blockIdx.x,
        A0,W0,ldw0,K0, A1,W1,ldw1,K1, A2,W2,ldw2,K2,
        bias, aux, aux_bf16, C, ldc, c_bf16, op, ncol, gemmBlocks, emaCar);
}

// dual-GEMM: blocks [0,256) = go (CONC@go^T -> GOUT);
//            blocks [256,512) = fg ([X,MED2]@fg^T sigmul -> MOUT)
__global__ __launch_bounds__(512) void gemm2_k(
    const u16* __restrict__ CONC, const u16* __restrict__ WGO,
    const float* __restrict__ go_b, u16* __restrict__ GOUT,
    const u16* __restrict__ Xh, const u16* __restrict__ WFG,
    const u16* __restrict__ MED2, const u16* __restrict__ WFG2,
    const float* __restrict__ fg_b, u16* __restrict__ MOUT)
{
    __shared__ u16 As[128*64];
    __shared__ u16 Ws[64*64];
    if ((int)blockIdx.x < 256){
        gemm_body(As, Ws, blockIdx.x,
            CONC, WGO, 256, 256,  nullptr,nullptr,0,0,  nullptr,nullptr,0,0,
            go_b, nullptr, 0, GOUT, 256, 1, OP_NONE, 4, 256, nullptr);
    } else {
        gemm_body(As, Ws, blockIdx.x - 256,
            Xh, WFG, 512, 256,  MED2, WFG2, 512, 256,  nullptr,nullptr,0,0,
            fg_b, MED2, 1, MOUT, 256, 1, OP_SIGMUL, 4, 256, nullptr);
    }
}

// ---------------------------------------------------------------------------
// Merged: MFMA banded attention (blocks 0..511) + scan1_p1 (blocks 512..767).
// ---------------------------------------------------------------------------
__global__ __launch_bounds__(256) void attn_scan_k(const u16* __restrict__ QKVG,
    u16* __restrict__ MED, float* __restrict__ CA, float* __restrict__ CC)
{
    const int tid = threadIdx.x;
    if (blockIdx.x >= 512){
        const int j = blockIdx.x - 512;
        const int c = j & (NC_-1), b = j >> 6;
        const int d = tid;
        const u16* base = QKVG + ((size_t)(b*T_ + c*LCH))*1280;
        float sgk=0.f, sgkv=0.f;
        for (int t=0;t<LCH;++t){
            float gk = bfu(base[(size_t)t*1280 + 768 + d]);
            gk = gk > 0.f ? gk + 1.f : expf(gk);
            float gv = bfu(base[(size_t)t*1280 + 1024 + d]);
            sgk += gk; sgkv += gk*gv;
        }
        CA[((size_t)b*NC_ + c)*D_ + d] = sgk;
        CC[((size_t)b*NC_ + c)*D_ + d] = sgkv;
        return;
    }

    __shared__ u16 Kl[128*64];
    __shared__ u16 Ql[64*64];
    __shared__ u16 Vl[64*128];
    const int b = blockIdx.x >> 7, h = (blockIdx.x >> 5) & 3;
    const int t0 = (blockIdx.x & 31) * 64;
    const int kb0 = t0 - 64;

    {
        const int r0 = tid >> 3, c8 = (tid & 7) * 8;
        #pragma unroll
        for (int rep=0;rep<4;++rep){
            const int r = r0 + rep*32;
            const int kg = kb0 + r;
            uint4 pk = {0,0,0,0}, pv = {0,0,0,0};
            if (kg >= 0){
                const u16* gp = QKVG + ((size_t)(b*T_ + kg))*1280 + h*HD_ + c8;
                pk = *(const uint4*)(gp + 256);
                pv = *(const uint4*)(gp + 512);
            }
            *(uint4*)&Kl[(r*64 + c8) ^ ((r&7)<<3)] = pk;
            const u16* pvu = (const u16*)&pv;
            #pragma unroll
            for (int j=0;j<8;++j){
                const int d = c8 + j;
                Vl[(d*128 + r) ^ ((d&15)<<3)] = pvu[j];
            }
        }
        #pragma unroll
        for (int rep=0;rep<2;++rep){
            const int r = r0 + rep*32;
            uint4 pq = *(const uint4*)(QKVG + ((size_t)(b*T_ + t0 + r))*1280 + h*HD_ + c8);
            *(uint4*)&Ql[(r*64 + c8) ^ ((r&7)<<3)] = pq;
        }
    }
    __syncthreads();

    const int lane = tid & 63, w = tid >> 6;
    const int l15 = lane & 15, l4 = lane >> 4;

    short8 bq[2];
    {
        const int qr = w*16 + l15;
        bq[0] = *(const short8*)&Ql[(qr*64 +      l4*8) ^ ((qr&7)<<3)];
        bq[1] = *(const short8*)&Ql[(qr*64 + 32 + l4*8) ^ ((qr&7)<<3)];
    }

    f32x4 s[8];
    #pragma unroll
    for (int kf=0;kf<8;++kf){
        const int kr = kf*16 + l15;
        short8 a0 = *(const short8*)&Kl[(kr*64 +      l4*8) ^ ((kr&7)<<3)];
        short8 a1 = *(const short8*)&Kl[(kr*64 + 32 + l4*8) ^ ((kr&7)<<3)];
        f32x4 acc = (f32x4){0.f,0.f,0.f,0.f};
        acc = __builtin_amdgcn_mfma_f32_16x16x32_bf16(a0, bq[0], acc, 0,0,0);
        acc = __builtin_amdgcn_mfma_f32_16x16x32_bf16(a1, bq[1], acc, 0,0,0);
        s[kf] = acc;
    }

    const int qg = t0 + w*16 + l15;
    float m = -1e30f;
    #pragma unroll
    for (int kf=0;kf<8;++kf){
        #pragma unroll
        for (int j=0;j<4;++j){
            const int kg = kb0 + kf*16 + l4*4 + j;
            const int diff = qg - kg;
            const float v = (kg >= 0 && diff >= 0 && diff < 64) ? s[kf][j]*0.125f : -1e30f;
            s[kf][j] = v;
            m = fmaxf(m, v);
        }
    }
    m = fmaxf(m, __shfl_xor(m,16));
    m = fmaxf(m, __shfl_xor(m,32));
    float lsum = 0.f;
    unsigned lo[8], hi[8];
    #pragma unroll
    for (int kf=0;kf<8;++kf){
        const float p0 = expf(s[kf][0]-m), p1 = expf(s[kf][1]-m);
        const float p2 = expf(s[kf][2]-m), p3 = expf(s[kf][3]-m);
        lsum += (p0+p1)+(p2+p3);
        lo[kf] = pk2(p0,p1);
        hi[kf] = pk2(p2,p3);
    }
    lsum += __shfl_xor(lsum,16);
    lsum += __shfl_xor(lsum,32);
    const float inv = 1.f/lsum;

    f32x4 o[4];
    #pragma unroll
    for (int df=0;df<4;++df) o[df] = (f32x4){0.f,0.f,0.f,0.f};
    const int baseLane = l15 + ((l4&1)<<5);
    const bool hiHalf = (l4>>1) != 0;
    #pragma unroll
    for (int kb=0;kb<4;++kb){
        const int x0 = __shfl((int)lo[2*kb],   baseLane);
        const int x1 = __shfl((int)hi[2*kb],   baseLane);
        const int x2 = __shfl((int)lo[2*kb],   baseLane+16);
        const int x3 = __shfl((int)hi[2*kb],   baseLane+16);
        const int y0 = __shfl((int)lo[2*kb+1], baseLane);
        const int y1 = __shfl((int)hi[2*kb+1], baseLane);
        const int y2 = __shfl((int)lo[2*kb+1], baseLane+16);
        const int y3 = __shfl((int)hi[2*kb+1], baseLane+16);
        int4 afi;
        afi.x = hiHalf ? y0 : x0;
        afi.y = hiHalf ? y1 : x1;
        afi.z = hiHalf ? y2 : x2;
        afi.w = hiHalf ? y3 : x3;
        union { int4 i; short8 s; } cv; cv.i = afi;
        #pragma unroll
        for (int df=0;df<4;++df){
            const int vr = df*16 + l15;
            short8 bv = *(const short8*)&Vl[(vr*128 + kb*32 + l4*8) ^ ((vr&15)<<3)];
            o[df] = __builtin_amdgcn_mfma_f32_16x16x32_bf16(cv.s, bv, o[df], 0,0,0);
        }
    }

    #pragma unroll
    for (int j=0;j<4;++j){
        const float invj = __shfl(inv, l4*4 + j);
        const int mrow = b*T_ + t0 + w*16 + l4*4 + j;
        u16* op = MED + (size_t)mrow*D_ + h*HD_ + l15;
        #pragma unroll
        for (int df=0;df<4;++df)
            op[df*16] = bf1(o[df][j] * invj);
    }
}

// ---------------------------------------------------------------------------
// Fused LN1 + gsum-EMA chunk aggregate.
// ---------------------------------------------------------------------------
__global__ __launch_bounds__(256) void ln1ema_k(const u16* __restrict__ in,
    const float* __restrict__ g, const float* __restrict__ b,
    u16* __restrict__ out, float* __restrict__ CARRY)
{
    __shared__ float wacc[4][256];
    const int c = blockIdx.x, bb = blockIdx.y;
    const int w = threadIdx.x >> 6, lane = threadIdx.x & 63;
    const int db = lane*4;
    const int row0 = bb*T_ + c*LCH;
    float acc0=0.f, acc1=0.f, acc2=0.f, acc3=0.f;
    #pragma unroll
    for (int it=0; it<8; ++it){
        const int r = it*4 + w;
        uint2 u = *(const uint2*)(in + (size_t)(row0 + r)*D_ + db);
        float x0=bfu((u16)(u.x&0xffff)), x1=bfu((u16)(u.x>>16));
        float x2=bfu((u16)(u.y&0xffff)), x3=bfu((u16)(u.y>>16));
        float s  = x0+x1+x2+x3;
        float s2 = x0*x0+x1*x1+x2*x2+x3*x3;
        #pragma unroll
        for (int o=1;o<64;o<<=1){ s += __shfl_xor(s,o); s2 += __shfl_xor(s2,o); }
        float mean = s*(1.f/256.f);
        float var  = s2*(1.f/256.f) - mean*mean;
        float rs = rsqrtf(var + 1e-5f);
        float y0=(x0-mean)*rs*g[db+0]+b[db+0];
        float y1=(x1-mean)*rs*g[db+1]+b[db+1];
        float y2=(x2-mean)*rs*g[db+2]+b[db+2];
        float y3=(x3-mean)*rs*g[db+3]+b[db+3];
        *(uint2*)(out + (size_t)(row0+r)*D_ + db) = (uint2){ pk2(y0,y1), pk2(y2,y3) };
        const float wt = 0.1f*powf(0.9f, (float)(31-r));
        acc0 += wt*y0; acc1 += wt*y1; acc2 += wt*y2; acc3 += wt*y3;
    }
    wacc[w][db+0]=acc0; wacc[w][db+1]=acc1; wacc[w][db+2]=acc2; wacc[w][db+3]=acc3;
    __syncthreads();
    const int d = threadIdx.x;
    CARRY[((size_t)bb*NC_ + c)*D_ + d] =
        wacc[0][d] + wacc[1][d] + wacc[2][d] + wacc[3][d];
}

// ---------------------------------------------------------------------------
// Fused state-EMA replay + LN3 (+LN4 on the final row).
// ---------------------------------------------------------------------------
__global__ __launch_bounds__(256) void ema_ln3_k(const u16* __restrict__ X,
    const float* __restrict__ CARRY, const float* __restrict__ SEQ,
    const float* __restrict__ g3, const float* __restrict__ b3, u16* __restrict__ states,
    const float* __restrict__ g4, const float* __restrict__ b4, float* __restrict__ fsout)
{
    __shared__ float vals[LCH][256];
    __shared__ float mv[LCH][2];
    __shared__ float st4[256];
    __shared__ float red[8];
    const int d = threadIdx.x, c = blockIdx.x, bb = blockIdx.y;
    const float dL = powf(0.9f, (float)LCH);
    float a = 0.f;
    for (int cc=0; cc<c; ++cc) a = CARRY[((size_t)bb*NC_ + cc)*D_ + d] + dL*a;
    const float ss = SEQ[bb*D_ + d];
    float dp = powf(0.9f, (float)(c*LCH + 1));
    const u16* xp = X + ((size_t)(bb*T_ + c*LCH))*D_ + d;
    for (int t=0;t<LCH;++t){
        a = 0.9f*a + bfu(xp[(size_t)t*D_]);
        vals[t][d] = fmaf(ss, dp, a);
        dp *= 0.9f;
    }
    __syncthreads();
    {
        const int r = threadIdx.x >> 3, seg = threadIdx.x & 7;
        float s=0.f, s2=0.f;
        #pragma unroll
        for (int j=0;j<32;++j){ float v = vals[r][seg*32+j]; s += v; s2 += v*v; }
        s += __shfl_xor(s,1); s2 += __shfl_xor(s2,1);
        s += __shfl_xor(s,2); s2 += __shfl_xor(s2,2);
        s += __shfl_xor(s,4); s2 += __shfl_xor(s2,4);
        if (seg == 0){
            float mean = s*(1.f/256.f);
            float var  = s2*(1.f/256.f) - mean*mean;
            mv[r][0] = mean; mv[r][1] = rsqrtf(var + 1e-5f);
        }
    }
    __syncthreads();
    const float gd = g3[d], bd = b3[d];
    const bool isLast = (c == NC_-1);
    u16* sp = states + ((size_t)(bb*T_ + c*LCH))*D_ + d;
    for (int t=0;t<LCH;++t){
        float st = (vals[t][d] - mv[t][0])*mv[t][1]*gd + bd;
        sp[(size_t)t*D_] = bf1(st);
        if (isLast && t == LCH-1) st4[d] = st;
    }
    if (isLast){
        __syncthreads();
        float v = st4[d];
        float s = v, s2 = v*v;
        #pragma unroll
        for (int o=1;o<64;o<<=1){ s += __shfl_xor(s,o); s2 += __shfl_xor(s2,o); }
        if ((threadIdx.x & 63) == 0){ red[threadIdx.x>>6] = s; red[4+(threadIdx.x>>6)] = s2; }
        __syncthreads();
        float S  = red[0]+red[1]+red[2]+red[3];
        float S2 = red[4]+red[5]+red[6]+red[7];
        float m2 = S*(1.f/256.f);
        float r2 = rsqrtf(S2*(1.f/256.f) - m2*m2 + 1e-5f);
        fsout[bb*D_ + d] = (st4[d]-m2)*r2*g4[d] + b4[d];
    }
}

// ---------------------------------------------------------------------------
// LN2: bf16 in, fp32 out (final pr_out).
// ---------------------------------------------------------------------------
__global__ __launch_bounds__(256) void ln2h_k(const u16* __restrict__ in,
    const float* __restrict__ g, const float* __restrict__ b, float* __restrict__ out)
{
    int row  = blockIdx.x*4 + (threadIdx.x>>6);
    int lane = threadIdx.x & 63;
    uint2 u = *(const uint2*)(in + (size_t)row*D_ + lane*4);
    float x0=bfu((u16)(u.x&0xffff)), x1=bfu((u16)(u.x>>16));
    float x2=bfu((u16)(u.y&0xffff)), x3=bfu((u16)(u.y>>16));
    float s  = x0+x1+x2+x3;
    float s2 = x0*x0+x1*x1+x2*x2+x3*x3;
    #pragma unroll
    for (int o=1;o<64;o<<=1){ s += __shfl_xor(s,o); s2 += __shfl_xor(s2,o); }
    float mean = s * (1.f/256.f);
    float var  = s2 * (1.f/256.f) - mean*mean;
    float rs = rsqrtf(var + 1e-5f);
    int db = lane*4;
    float4 r;
    r.x=(x0-mean)*rs*g[db+0]+b[db+0];
    r.y=(x1-mean)*rs*g[db+1]+b[db+1];
    r.z=(x2-mean)*rs*g[db+2]+b[db+2];
    r.w=(x3-mean)*rs*g[db+3]+b[db+3];
    *(float4*)(out + (size_t)row*D_ + db) = r;
}

// ---------------------------------------------------------------------------
extern "C" void kernel_launch(void* const* d_in, const int* in_sizes, int n_in,
                              void* d_out, int out_size, void* d_ws, size_t ws_size,
                              hipStream_t stream)
{
    const float* X     = (const float*)d_in[0];
    const float* SEQ   = (const float*)d_in[1];
    const float* conv_w= (const float*)d_in[3];
    const float* conv_b= (const float*)d_in[4];
    const float* qkv_w = (const float*)d_in[5];
    const float* qkv_b = (const float*)d_in[6];
    const float* mo_w  = (const float*)d_in[7];
    const float* mo_b  = (const float*)d_in[8];
    const float* fg_w  = (const float*)d_in[9];
    const float* fg_b  = (const float*)d_in[10];
    const float* gkv_w = (const float*)d_in[11];
    const float* gkv_b = (const float*)d_in[12];
    const float* go_w  = (const float*)d_in[13];
    const float* go_b  = (const float*)d_in[14];
    const float* comb_w= (const float*)d_in[15];
    const float* comb_b= (const float*)d_in[16];
    const float* ffn1_w= (const float*)d_in[17];
    const float* ffn1_b= (const float*)d_in[18];
    const float* ffn2_w= (const float*)d_in[19];
    const float* ffn2_b= (const float*)d_in[20];
    const float* tr1_w = (const float*)d_in[21];
    const float* tr1_b = (const float*)d_in[22];
    const float* tr2_w = (const float*)d_in[23];
    const float* tr2_b = (const float*)d_in[24];
    const float* p2s_w = (const float*)d_in[25];
    const float* p2s_b = (const float*)d_in[26];
    const float* s2p_w = (const float*)d_in[27];
    const float* s2p_b = (const float*)d_in[28];
    const float* ln1_g = (const float*)d_in[29];
    const float* ln1_b = (const float*)d_in[30];
    const float* ln2_g = (const float*)d_in[31];
    const float* ln2_b = (const float*)d_in[32];
    const float* ln3_g = (const float*)d_in[33];
    const float* ln3_b = (const float*)d_in[34];
    const float* ln4_g = (const float*)d_in[35];
    const float* ln4_b = (const float*)d_in[36];

    // -------- workspace carve (256-byte aligned chunks) --------
    char* p = (char*)d_ws;
    auto alloc = [&](size_t bytes)->char*{ char* r = p; p += (bytes + 255) & ~(size_t)255; return r; };

    u16*   QKVG = (u16*)  alloc((size_t)M_*1280*2);
    u16*   Wh   = (u16*)  alloc((size_t)NWELEM*2);
    float* bq   = (float*)alloc(1280*4);
    u16*   Xh   = (u16*)  alloc((size_t)M_*256*2);
    u16*   MED  = (u16*)  alloc((size_t)M_*256*2);
    u16*   MED2 = (u16*)  alloc((size_t)M_*256*2);
    u16*   LH   = (u16*)  alloc((size_t)M_*256*2);
    u16*   CONC = (u16*)  alloc((size_t)M_*256*2);
    u16*   GOUT = (u16*)  alloc((size_t)M_*256*2);
    u16*   MOUT = (u16*)  alloc((size_t)M_*256*2);
    u16*   PRE1h= (u16*)  alloc((size_t)M_*256*2);
    u16*   PRh  = (u16*)  alloc((size_t)M_*256*2);
    u16*   GSUM = (u16*)  alloc((size_t)M_*256*2);
    u16*   CS1  = (u16*)  alloc((size_t)M_*256*2);
    u16*   H1   = (u16*)  alloc((size_t)M_*512*2);
    u16*   SCALEDh=(u16*) alloc((size_t)M_*256*2);
    u16*   STATESh=(u16*) alloc((size_t)M_*256*2);
    u16*   FFNIN= (u16*)  alloc((size_t)M_*256*2);
    u16*   H2   = (u16*)  alloc((size_t)M_*1024*2);
    u16*   PRE2h= (u16*)  alloc((size_t)M_*256*2);
    float* CAR0 = (float*)alloc((size_t)B_*NC_*D_*4);
    float* CAR1 = (float*)alloc((size_t)B_*NC_*D_*4);

    float* out_pr = (float*)d_out;
    float* out_fs = out_pr + (size_t)M_*256;
    float* out_tj = out_fs + B_*256;

    const dim3 blk256(256), blk512(512);
    const dim3 scan_grid(NC_, B_);
    const int NRg = M_/128;   // 64 row tiles

    // 0. convert weights + X to bf16, bias concat, fused depthwise conv -> LH
    cvt_conv_k<<<dim3(CVT_BLKS + CONV_BLKS), blk256, 0, stream>>>(
        qkv_w, gkv_w, qkv_b, gkv_b, mo_w, fg_w, go_w, comb_w,
        ffn1_w, ffn2_w, tr1_w, tr2_w, p2s_w, s2p_w, X, conv_w, conv_b,
        Wh, Xh, bq, LH);
    // 1. fused qkv+gkv projection -> QKVG (bf16)
    gemm_k<<<dim3(NRg*20), blk512, 0, stream>>>(
        Xh, Wh+OFF_QKV, 256, 256,  nullptr,nullptr,0,0,  nullptr,nullptr,0,0,
        bq, nullptr, 0, QKVG, 1280, 1, OP_NONE, 20,
        NRg*20, 0, nullptr, nullptr, nullptr, nullptr, nullptr, nullptr);
    // 2. banded attention -> MED  ||  scan1_p1 -> CAR0/CAR1
    attn_scan_k<<<dim3(512 + 256), blk256, 0, stream>>>(QKVG, MED, CAR0, CAR1);
    // 3. mo projection -> MED2  ||  scan1_p3 -> CONC
    gemm_k<<<dim3(NRg*4 + 256), blk512, 0, stream>>>(
        MED, Wh+OFF_MO, 256, 256,  nullptr,nullptr,0,0,  nullptr,nullptr,0,0,
        mo_b, nullptr, 0, MED2, 256, 1, OP_NONE, 4,
        NRg*4, 1, QKVG, CAR0, CAR1, CONC, nullptr, nullptr);
    // 4. dual: global_out -> GOUT || medium_out -> MOUT
    gemm2_k<<<dim3(512), blk512, 0, stream>>>(
        CONC, Wh+OFF_GO, go_b, GOUT,
        Xh, Wh+OFF_FG, MED2, Wh+OFF_FG+256, fg_b, MOUT);
    // 5. pre_ln1 = X + [LH,MOUT,GOUT]@comb^T + b -> PRE1h bf16
    gemm_k<<<dim3(NRg*4), blk512, 0, stream>>>(
        LH, Wh+OFF_COMB, 768, 256,  MOUT, Wh+OFF_COMB+256, 768, 256,  GOUT, Wh+OFF_COMB+512, 768, 256,
        comb_b, X, 0, PRE1h, 256, 1, OP_ADDAUX, 4,
        NRg*4, 0, nullptr, nullptr, nullptr, nullptr, nullptr, nullptr);
    // 6. pr = LN1 -> PRh bf16, fused gsum EMA p1 -> CAR0
    ln1ema_k<<<scan_grid, blk256, 0, stream>>>(PRE1h, ln1_g, ln1_b, PRh, CAR0);
    // 7. cs1 = pr + 0.3*(pr@p2s^T + b) -> CS1  ||  gsum EMA replay -> GSUM + traj
    gemm_k<<<dim3(NRg*4 + 256), blk512, 0, stream>>>(
        PRh, Wh+OFF_P2S, 256, 256,  nullptr,nullptr,0,0,  nullptr,nullptr,0,0,
        p2s_b, PRh, 1, CS1, 256, 1, OP_AXPBY, 4,
        NRg*4, 2, PRh, CAR0, nullptr, GSUM, out_tj, nullptr);
    // 8. H1 = gelu(cs1@tr1a + gsum@tr1b + b) bf16
    gemm_k<<<dim3(NRg*8), blk512, 0, stream>>>(
        CS1, Wh+OFF_TR1, 512, 256,  GSUM, Wh+OFF_TR1+256, 512, 256,  nullptr,nullptr,0,0,
        tr1_b, nullptr, 0, H1, 512, 1, OP_GELU, 8,
        NRg*8, 0, nullptr, nullptr, nullptr, nullptr, nullptr, nullptr);
    // 9. scaled = 0.5*tanh(H1@tr2^T + b) -> SCALEDh bf16, fused state-EMA p1 -> CAR0
    gemm_k<<<dim3(NRg*4), blk512, 0, stream>>>(
        H1, Wh+OFF_TR2, 512, 512,  nullptr,nullptr,0,0,  nullptr,nullptr,0,0,
        tr2_b, nullptr, 0, SCALEDh, 256, 1, OP_TANHHALF, 4,
        NRg*4, 0, nullptr, nullptr, nullptr, nullptr, nullptr, CAR0);
    // 10. fused state EMA replay + LN3 + LN4 -> STATESh bf16, out_fs
    ema_ln3_k<<<scan_grid, blk256, 0, stream>>>(
        SCALEDh, CAR0, SEQ, ln3_g, ln3_b, STATESh, ln4_g, ln4_b, out_fs);
    // 11. ffn_in = pr + 0.3*(states@s2p^T + b) -> FFNIN bf16
    gemm_k<<<dim3(NRg*4), blk512, 0, stream>>>(
        STATESh, Wh+OFF_S2P, 256, 256,  nullptr,nullptr,0,0,  nullptr,nullptr,0,0,
        s2p_b, PRh, 1, FFNIN, 256, 1, OP_AXPBY, 4,
        NRg*4, 0, nullptr, nullptr, nullptr, nullptr, nullptr, nullptr);
    // 12. H2 = gelu(ffn_in@ffn1^T + b) bf16
    gemm_k<<<dim3(NRg*16), blk512, 0, stream>>>(
        FFNIN, Wh+OFF_FFN1, 256, 256,  nullptr,nullptr,0,0,  nullptr,nullptr,0,0,
        ffn1_b, nullptr, 0, H2, 1024, 1, OP_GELU, 16,
        NRg*16, 0, nullptr, nullptr, nullptr, nullptr, nullptr, nullptr);
    // 13. pre_ln2 = pr + H2@ffn2^T + b -> PRE2h bf16
    gemm_k<<<dim3(NRg*4), blk512, 0, stream>>>(
        H2, Wh+OFF_FFN2, 1024, 1024,  nullptr,nullptr,0,0,  nullptr,nullptr,0,0,
        ffn2_b, PRh, 1, PRE2h, 256, 1, OP_ADDAUX, 4,
        NRg*4, 0, nullptr, nullptr, nullptr, nullptr, nullptr, nullptr);
    // 14. pr_out = LN2 -> d_out
    ln2h_k<<<dim3(M_/4), blk256, 0, stream>>>(PRE2h, ln2_g, ln2_b, out_pr);
}